// Round 1
// baseline (511.277 us; speedup 1.0000x reference)
//
#include <hip/hip_runtime.h>
#include <math.h>

#define CH 256

// ---------------------------------------------------------------- utilities
__device__ inline float warp_sum64(float v) {
    v += __shfl_xor(v, 32, 64);
    v += __shfl_xor(v, 16, 64);
    v += __shfl_xor(v, 8, 64);
    v += __shfl_xor(v, 4, 64);
    v += __shfl_xor(v, 2, 64);
    v += __shfl_xor(v, 1, 64);
    return v;
}

// ------------------------------------------------- per-edge GN stats (768, 32 groups of 24)
__global__ __launch_bounds__(256) void edge_stats_kernel(
    const float* __restrict__ x, const float* __restrict__ eattr,
    const int* __restrict__ rowi, const int* __restrict__ coli,
    float* __restrict__ mu, float* __restrict__ rs, int E)
{
    __shared__ float sb[768];
    int e = blockIdx.x;
    int t = threadIdx.x;
    int r = rowi[e], c = coli[e];
    sb[t]       = x[r * CH + t];
    sb[256 + t] = x[c * CH + t];
    sb[512 + t] = eattr[e * CH + t];
    __syncthreads();
    if (t < 32) {
        float s = 0.f, s2 = 0.f;
        const float* p = &sb[t * 24];
        #pragma unroll
        for (int i = 0; i < 24; i++) { float v = p[i]; s += v; s2 += v * v; }
        float m = s * (1.f / 24.f);
        float var = s2 * (1.f / 24.f) - m * m;
        mu[e * 32 + t] = m;
        rs[e * 32 + t] = rsqrtf(var + 1e-5f);
    }
}

// ------------------------------------------------- generic tiled fp32 GEMM
// AMODE 0: A = plain row-major [M,K] pointer
// AMODE 1: A = virtual relu(groupnorm(concat(x[row], x[col], edge_attr))) [E,768]
template <int AMODE>
__global__ __launch_bounds__(256) void gemm_kernel(
    const float* __restrict__ A, const float* __restrict__ B,
    const float* __restrict__ bias, const float* __restrict__ res,
    float* __restrict__ C, int M, int K, int Nc,
    const float* __restrict__ xg, const float* __restrict__ eattr,
    const int* __restrict__ rowi, const int* __restrict__ coli,
    const float* __restrict__ mu, const float* __restrict__ rs,
    const float* __restrict__ gng, const float* __restrict__ gnb)
{
    const int BM = 64, BN = 64, BK = 16;
    __shared__ float As[BK][BM + 4];   // transposed A tile, padded (stride 68 floats)
    __shared__ float Bs[BK][BN];
    int t = threadIdx.x;
    int row0 = blockIdx.y * BM;
    int col0 = blockIdx.x * BN;
    int tr = t >> 4, tc = t & 15;
    int m0 = tr * 4, n0 = tc * 4;
    int lm = t >> 2, lk4 = (t & 3) * 4;      // A-load: row lm, k offset lk4 (float4)
    int lbk = t >> 4, lbn = (t & 15) * 4;    // B-load: row lbk, col lbn (float4)
    float acc[4][4];
    #pragma unroll
    for (int i = 0; i < 4; i++)
        #pragma unroll
        for (int j = 0; j < 4; j++) acc[i][j] = 0.f;

    int am = row0 + lm;
    int ae = am < M ? am : M - 1;   // clamped for safe gathers
    int asrc = 0, asrc2 = 0;
    if constexpr (AMODE == 1) { asrc = rowi[ae]; asrc2 = coli[ae]; }

    for (int k0 = 0; k0 < K; k0 += BK) {
        int kk = k0 + lk4;
        float4 av;
        if constexpr (AMODE == 0) {
            if (am < M) av = *(const float4*)&A[(long)am * K + kk];
            else { av.x = av.y = av.z = av.w = 0.f; }
        } else {
            const float* src;
            if (kk < 256)      src = &xg[(long)asrc * CH + kk];
            else if (kk < 512) src = &xg[(long)asrc2 * CH + kk - 256];
            else               src = &eattr[(long)ae * CH + kk - 512];
            av = *(const float4*)src;
            int gi = kk / 24;   // float4 never crosses a group boundary (24 % 4 == 0)
            float mm = mu[ae * 32 + gi], rr = rs[ae * 32 + gi];
            float4 gg = *(const float4*)&gng[kk];
            float4 bb = *(const float4*)&gnb[kk];
            av.x = fmaxf((av.x - mm) * rr * gg.x + bb.x, 0.f);
            av.y = fmaxf((av.y - mm) * rr * gg.y + bb.y, 0.f);
            av.z = fmaxf((av.z - mm) * rr * gg.z + bb.z, 0.f);
            av.w = fmaxf((av.w - mm) * rr * gg.w + bb.w, 0.f);
            if (am >= M) { av.x = av.y = av.z = av.w = 0.f; }
        }
        As[lk4 + 0][lm] = av.x;
        As[lk4 + 1][lm] = av.y;
        As[lk4 + 2][lm] = av.z;
        As[lk4 + 3][lm] = av.w;
        *(float4*)&Bs[lbk][lbn] = *(const float4*)&B[(long)(k0 + lbk) * Nc + col0 + lbn];
        __syncthreads();
        #pragma unroll
        for (int kq = 0; kq < BK; kq++) {
            float4 a = *(const float4*)&As[kq][m0];
            float4 b = *(const float4*)&Bs[kq][n0];
            acc[0][0] += a.x * b.x; acc[0][1] += a.x * b.y; acc[0][2] += a.x * b.z; acc[0][3] += a.x * b.w;
            acc[1][0] += a.y * b.x; acc[1][1] += a.y * b.y; acc[1][2] += a.y * b.z; acc[1][3] += a.y * b.w;
            acc[2][0] += a.z * b.x; acc[2][1] += a.z * b.y; acc[2][2] += a.z * b.z; acc[2][3] += a.z * b.w;
            acc[3][0] += a.w * b.x; acc[3][1] += a.w * b.y; acc[3][2] += a.w * b.z; acc[3][3] += a.w * b.w;
        }
        __syncthreads();
    }
    float4 bv = *(const float4*)&bias[col0 + n0];
    #pragma unroll
    for (int i = 0; i < 4; i++) {
        int rr2 = row0 + m0 + i;
        if (rr2 < M) {
            float4 o;
            o.x = acc[i][0] + bv.x; o.y = acc[i][1] + bv.y;
            o.z = acc[i][2] + bv.z; o.w = acc[i][3] + bv.w;
            if (res) {
                float4 rv = *(const float4*)&res[(long)rr2 * Nc + col0 + n0];
                o.x += rv.x; o.y += rv.y; o.z += rv.z; o.w += rv.w;
            }
            *(float4*)&C[(long)rr2 * Nc + col0 + n0] = o;
        }
    }
}

// ------------------------------------------------- GN(256ch, 32 groups of 8) + ReLU in place
__global__ __launch_bounds__(256) void gn_relu_kernel(
    float* __restrict__ h, const float* __restrict__ gamma,
    const float* __restrict__ beta, int rows)
{
    int t = threadIdx.x;
    int r = blockIdx.x * 8 + (t >> 5);
    int g = t & 31;
    if (r >= rows) return;
    long base = (long)r * CH + g * 8;
    float4 v0 = *(float4*)&h[base];
    float4 v1 = *(float4*)&h[base + 4];
    float s  = v0.x + v0.y + v0.z + v0.w + v1.x + v1.y + v1.z + v1.w;
    float s2 = v0.x*v0.x + v0.y*v0.y + v0.z*v0.z + v0.w*v0.w
             + v1.x*v1.x + v1.y*v1.y + v1.z*v1.z + v1.w*v1.w;
    float m = s * 0.125f;
    float var = s2 * 0.125f - m * m;
    float rsd = rsqrtf(var + 1e-5f);
    float4 g0 = *(const float4*)&gamma[g * 8];
    float4 g1 = *(const float4*)&gamma[g * 8 + 4];
    float4 b0 = *(const float4*)&beta[g * 8];
    float4 b1 = *(const float4*)&beta[g * 8 + 4];
    v0.x = fmaxf((v0.x - m) * rsd * g0.x + b0.x, 0.f);
    v0.y = fmaxf((v0.y - m) * rsd * g0.y + b0.y, 0.f);
    v0.z = fmaxf((v0.z - m) * rsd * g0.z + b0.z, 0.f);
    v0.w = fmaxf((v0.w - m) * rsd * g0.w + b0.w, 0.f);
    v1.x = fmaxf((v1.x - m) * rsd * g1.x + b1.x, 0.f);
    v1.y = fmaxf((v1.y - m) * rsd * g1.y + b1.y, 0.f);
    v1.z = fmaxf((v1.z - m) * rsd * g1.z + b1.z, 0.f);
    v1.w = fmaxf((v1.w - m) * rsd * g1.w + b1.w, 0.f);
    *(float4*)&h[base] = v0;
    *(float4*)&h[base + 4] = v1;
}

// ------------------------------------------------- cat[N,512] = [relu(gn(x)) | go]
__global__ __launch_bounds__(256) void node_cat_kernel(
    const float* __restrict__ x, const float* __restrict__ go,
    const float* __restrict__ gamma, const float* __restrict__ beta,
    float* __restrict__ cat, int N)
{
    int t = threadIdx.x;
    int r = blockIdx.x * 8 + (t >> 5);
    int g = t & 31;
    if (r >= N) return;
    long xb = (long)r * CH + g * 8;
    float4 v0 = *(const float4*)&x[xb];
    float4 v1 = *(const float4*)&x[xb + 4];
    float s  = v0.x + v0.y + v0.z + v0.w + v1.x + v1.y + v1.z + v1.w;
    float s2 = v0.x*v0.x + v0.y*v0.y + v0.z*v0.z + v0.w*v0.w
             + v1.x*v1.x + v1.y*v1.y + v1.z*v1.z + v1.w*v1.w;
    float m = s * 0.125f;
    float var = s2 * 0.125f - m * m;
    float rsd = rsqrtf(var + 1e-5f);
    float4 g0 = *(const float4*)&gamma[g * 8];
    float4 g1 = *(const float4*)&gamma[g * 8 + 4];
    float4 b0 = *(const float4*)&beta[g * 8];
    float4 b1 = *(const float4*)&beta[g * 8 + 4];
    v0.x = fmaxf((v0.x - m) * rsd * g0.x + b0.x, 0.f);
    v0.y = fmaxf((v0.y - m) * rsd * g0.y + b0.y, 0.f);
    v0.z = fmaxf((v0.z - m) * rsd * g0.z + b0.z, 0.f);
    v0.w = fmaxf((v0.w - m) * rsd * g0.w + b0.w, 0.f);
    v1.x = fmaxf((v1.x - m) * rsd * g1.x + b1.x, 0.f);
    v1.y = fmaxf((v1.y - m) * rsd * g1.y + b1.y, 0.f);
    v1.z = fmaxf((v1.z - m) * rsd * g1.z + b1.z, 0.f);
    v1.w = fmaxf((v1.w - m) * rsd * g1.w + b1.w, 0.f);
    long cb = (long)r * (2 * CH) + g * 8;
    *(float4*)&cat[cb] = v0;
    *(float4*)&cat[cb + 4] = v1;
    float4 c0 = *(const float4*)&go[xb];
    float4 c1 = *(const float4*)&go[xb + 4];
    *(float4*)&cat[cb + CH] = c0;
    *(float4*)&cat[cb + CH + 4] = c1;
}

// ------------------------------------------------- CSR build
__global__ void zero_kernel(int* __restrict__ counts, float* __restrict__ vbar, int N)
{
    int i = blockIdx.x * blockDim.x + threadIdx.x;
    if (i < N) counts[i] = 0;
    if (i < CH) vbar[i] = 0.f;
}

__global__ void count_kernel(const int* __restrict__ coli, int* __restrict__ counts, int E)
{
    int e = blockIdx.x * blockDim.x + threadIdx.x;
    if (e < E) atomicAdd(&counts[coli[e]], 1);
}

__global__ __launch_bounds__(1024) void scan_kernel(
    const int* __restrict__ counts, int* __restrict__ offsets,
    int* __restrict__ cursor, int N)
{
    __shared__ int s[1024];
    int t = threadIdx.x;
    int a = (2 * t     < N) ? counts[2 * t]     : 0;
    int b = (2 * t + 1 < N) ? counts[2 * t + 1] : 0;
    s[t] = a + b;
    __syncthreads();
    for (int off = 1; off < 1024; off <<= 1) {
        int v = (t >= off) ? s[t - off] : 0;
        __syncthreads();
        s[t] += v;
        __syncthreads();
    }
    int excl = (t > 0) ? s[t - 1] : 0;
    if (2 * t < N)     { offsets[2 * t]     = excl;     cursor[2 * t]     = excl; }
    if (2 * t + 1 < N) { offsets[2 * t + 1] = excl + a; cursor[2 * t + 1] = excl + a; }
    if (t == 1023) offsets[N] = s[1023];
}

__global__ void fill_kernel(const int* __restrict__ coli, int* __restrict__ cursor,
                            int* __restrict__ elist, int E)
{
    int e = blockIdx.x * blockDim.x + threadIdx.x;
    if (e < E) {
        int p = atomicAdd(&cursor[coli[e]], 1);
        elist[p] = e;
    }
}

// ------------------------------------------------- column mean of v (for 0-degree nodes)
__global__ __launch_bounds__(256) void vbar_kernel(
    const float* __restrict__ vb, float* __restrict__ vbar, int E)
{
    int t = threadIdx.x;
    int per = (E + gridDim.x - 1) / gridDim.x;
    int e0 = blockIdx.x * per;
    int e1 = e0 + per; if (e1 > E) e1 = E;
    float s = 0.f;
    for (int e = e0; e < e1; e++) s += vb[(long)e * CH + t];
    atomicAdd(&vbar[t], s);
}

// ------------------------------------------------- per-node segment softmax attention
// block = 1 node; wave w = head w (64 lanes = 64 dims of the head)
__global__ __launch_bounds__(256) void attn_kernel(
    const float* __restrict__ qb, const float* __restrict__ kb,
    const float* __restrict__ vb, const int* __restrict__ offsets,
    const int* __restrict__ elist, const float* __restrict__ vbar,
    float* __restrict__ gbuf, int N, int E)
{
    int n = blockIdx.x;
    int c = threadIdx.x;      // channel = head*64 + dim; wave boundary == head boundary
    float qv = qb[(long)n * CH + c];
    int s0 = offsets[n], s1 = offsets[n + 1];
    float m = -INFINITY, l = 0.f, num = 0.f;
    for (int idx = s0; idx < s1; idx++) {
        int e = elist[idx];
        float s = warp_sum64(qv * kb[(long)e * CH + c]) * 0.125f;  // 1/sqrt(64)
        float mn = fmaxf(m, s);
        float sc = __expf(m - mn);   // m=-inf first iter -> 0
        float p  = __expf(s - mn);
        l = l * sc + p;
        num = num * sc + p * vb[(long)e * CH + c];
        m = mn;
    }
    float out;
    if (s1 > s0) out = num / l;
    else         out = vbar[c] * (1.f / (float)E);  // uniform softmax over ALL edges
    gbuf[(long)n * CH + c] = out;
}

// ================================================================ launch
extern "C" void kernel_launch(void* const* d_in, const int* in_sizes, int n_in,
                              void* d_out, int out_size, void* d_ws, size_t ws_size,
                              hipStream_t stream)
{
    const float* x       = (const float*)d_in[0];
    const int*   ei      = (const int*)d_in[1];
    const float* eattr   = (const float*)d_in[2];
    const float* gn_e1_g = (const float*)d_in[3];
    const float* gn_e1_b = (const float*)d_in[4];
    const float* We1     = (const float*)d_in[5];
    const float* be1     = (const float*)d_in[6];
    const float* gn_e2_g = (const float*)d_in[7];
    const float* gn_e2_b = (const float*)d_in[8];
    const float* We2     = (const float*)d_in[9];
    const float* be2     = (const float*)d_in[10];
    const float* gn_n_g  = (const float*)d_in[11];
    const float* gn_n_b  = (const float*)d_in[12];
    const float* Wq      = (const float*)d_in[13];
    const float* bq      = (const float*)d_in[14];
    const float* Wk      = (const float*)d_in[15];
    const float* bk      = (const float*)d_in[16];
    const float* Wv      = (const float*)d_in[17];
    const float* bv      = (const float*)d_in[18];
    const float* Wo      = (const float*)d_in[19];
    const float* bo      = (const float*)d_in[20];
    const float* Wn1     = (const float*)d_in[21];
    const float* bn1     = (const float*)d_in[22];
    const float* gn_n2_g = (const float*)d_in[23];
    const float* gn_n2_b = (const float*)d_in[24];
    const float* Wn2     = (const float*)d_in[25];
    const float* bn2     = (const float*)d_in[26];

    const int N = in_sizes[0] / CH;
    const int E = in_sizes[2] / CH;

    float* nout = (float*)d_out;                       // [N,256]
    float* eout = (float*)d_out + (size_t)N * CH;      // [E,256]

    float* w = (float*)d_ws;
    float* mu   = w; w += (size_t)E * 32;
    float* rs   = w; w += (size_t)E * 32;
    float* h1   = w; w += (size_t)E * CH;
    float* kbuf = w; w += (size_t)E * CH;
    float* vbuf = w; w += (size_t)E * CH;
    float* qbuf = w; w += (size_t)N * CH;
    float* gbuf = w; w += (size_t)N * CH;
    float* gob  = w; w += (size_t)N * CH;
    float* cat  = w; w += (size_t)N * 2 * CH;
    float* hn   = w; w += (size_t)N * CH;
    float* vbar = w; w += CH;
    int* counts  = (int*)w;
    int* offsets = counts + N;
    int* cursor  = offsets + (N + 1);
    int* elist   = cursor + N;

    const int* rowi = ei;
    const int* coli = ei + E;

    dim3 blk(256);
    dim3 gE(CH / 64, E / 64);                 // edge GEMMs (E % 64 == 0)
    dim3 gN(CH / 64, (N + 63) / 64);          // node GEMMs

    // ---- edge model ----
    edge_stats_kernel<<<E, blk, 0, stream>>>(x, eattr, rowi, coli, mu, rs, E);
    gemm_kernel<1><<<gE, blk, 0, stream>>>(nullptr, We1, be1, nullptr, h1, E, 3 * CH, CH,
                                           x, eattr, rowi, coli, mu, rs, gn_e1_g, gn_e1_b);
    gn_relu_kernel<<<E / 8, blk, 0, stream>>>(h1, gn_e2_g, gn_e2_b, E);
    gemm_kernel<0><<<gE, blk, 0, stream>>>(h1, We2, be2, eattr, eout, E, CH, CH,
                                           nullptr, nullptr, nullptr, nullptr,
                                           nullptr, nullptr, nullptr, nullptr);

    // ---- projections ----
    gemm_kernel<0><<<gE, blk, 0, stream>>>(eout, Wk, bk, nullptr, kbuf, E, CH, CH,
                                           nullptr, nullptr, nullptr, nullptr,
                                           nullptr, nullptr, nullptr, nullptr);
    gemm_kernel<0><<<gE, blk, 0, stream>>>(eout, Wv, bv, nullptr, vbuf, E, CH, CH,
                                           nullptr, nullptr, nullptr, nullptr,
                                           nullptr, nullptr, nullptr, nullptr);
    gemm_kernel<0><<<gN, blk, 0, stream>>>(x, Wq, bq, nullptr, qbuf, N, CH, CH,
                                           nullptr, nullptr, nullptr, nullptr,
                                           nullptr, nullptr, nullptr, nullptr);

    // ---- CSR over col + vbar ----
    zero_kernel<<<(N + 255) / 256, blk, 0, stream>>>(counts, vbar, N);
    count_kernel<<<(E + 255) / 256, blk, 0, stream>>>(coli, counts, E);
    scan_kernel<<<1, 1024, 0, stream>>>(counts, offsets, cursor, N);
    fill_kernel<<<(E + 255) / 256, blk, 0, stream>>>(coli, cursor, elist, E);
    vbar_kernel<<<64, blk, 0, stream>>>(vbuf, vbar, E);

    // ---- attention + output proj ----
    attn_kernel<<<N, blk, 0, stream>>>(qbuf, kbuf, vbuf, offsets, elist, vbar, gbuf, N, E);
    gemm_kernel<0><<<gN, blk, 0, stream>>>(gbuf, Wo, bo, nullptr, gob, N, CH, CH,
                                           nullptr, nullptr, nullptr, nullptr,
                                           nullptr, nullptr, nullptr, nullptr);

    // ---- node MLP ----
    node_cat_kernel<<<(N + 7) / 8, blk, 0, stream>>>(x, gob, gn_n_g, gn_n_b, cat, N);
    gemm_kernel<0><<<gN, blk, 0, stream>>>(cat, Wn1, bn1, nullptr, hn, N, 2 * CH, CH,
                                           nullptr, nullptr, nullptr, nullptr,
                                           nullptr, nullptr, nullptr, nullptr);
    gn_relu_kernel<<<(N + 7) / 8, blk, 0, stream>>>(hn, gn_n2_g, gn_n2_b, N);
    gemm_kernel<0><<<gN, blk, 0, stream>>>(hn, Wn2, bn2, x, nout, N, CH, CH,
                                           nullptr, nullptr, nullptr, nullptr,
                                           nullptr, nullptr, nullptr, nullptr);
}

// Round 2
// 359.428 us; speedup vs baseline: 1.4225x; 1.4225x over previous
//
#include <hip/hip_runtime.h>
#include <hip/hip_bf16.h>
#include <stdint.h>
#include <math.h>

#define CH 256

typedef __attribute__((ext_vector_type(8))) short short8;
typedef __attribute__((ext_vector_type(4))) float f32x4;

#define GL2LDS16(g, l) __builtin_amdgcn_global_load_lds(                       \
    (const __attribute__((address_space(1))) void*)(g),                        \
    (__attribute__((address_space(3))) void*)(l), 16, 0, 0)

__device__ inline short f2bf(float f) {
    __hip_bfloat16 h = __float2bfloat16(f);
    short s;
    __builtin_memcpy(&s, &h, 2);
    return s;
}

__device__ inline float warp_sum64(float v) {
    v += __shfl_xor(v, 32, 64);
    v += __shfl_xor(v, 16, 64);
    v += __shfl_xor(v, 8, 64);
    v += __shfl_xor(v, 4, 64);
    v += __shfl_xor(v, 2, 64);
    v += __shfl_xor(v, 1, 64);
    return v;
}

// ==================================================================== MFMA GEMM
// C[M,256] = A[M,K](bf16) x B[K,256] (given as Bt[256,K] bf16) + bias (+res)
// m97 structure: BMxBN tile, BK=32, 4 waves (2x2), 16x16x32 bf16 MFMA,
// global_load_lds width-16 staging, row-major [rows][32] LDS tiles.
template <int BM, int BN, int RES, int WBF>
__global__ __launch_bounds__(256) void mfma_gemm(
    const short* __restrict__ A, const short* __restrict__ Bt,
    const float* __restrict__ bias, const float* __restrict__ res,
    float* __restrict__ C, short* __restrict__ Cbf, int M, int K)
{
    constexpr int BK = 32;
    constexpr int HM = BM / 2, HN = BN / 2;   // per-wave sub-tile
    constexpr int FM = HM / 16, FN = HN / 16; // 16x16 frags per wave
    constexpr int PA = (BM * BK) / (256 * 8); // staging passes (16B x 256thr = 4KB)
    constexpr int PB = (BN * BK) / (256 * 8);
    __shared__ short As[BM * BK];
    __shared__ short Bs[BN * BK];

    const int t = threadIdx.x;
    const int wave = t >> 6, lane = t & 63;
    const int q = lane >> 4, l16 = lane & 15;
    const int row0 = blockIdx.y * BM;
    const int col0 = blockIdx.x * BN;
    const int wm = wave & 1, wn = wave >> 1;

    f32x4 acc[FM][FN];
    #pragma unroll
    for (int i = 0; i < FM; i++)
        #pragma unroll
        for (int j = 0; j < FN; j++) acc[i][j] = (f32x4){0.f, 0.f, 0.f, 0.f};

    for (int k0 = 0; k0 < K; k0 += BK) {
        #pragma unroll
        for (int p = 0; p < PA; p++) {
            int chunk = p * 256 + t;
            int r = chunk >> 2, ko = (chunk & 3) * 8;  // 4 chunks of 8 bf16 per 32-wide row
            int gr = row0 + r; if (gr >= M) gr = M - 1;
            const short* gsrc = A + (size_t)gr * K + k0 + ko;
            short* ldst = &As[(p * 256 + wave * 64) * 8];  // wave-uniform base + lane*16B
            GL2LDS16(gsrc, ldst);
        }
        #pragma unroll
        for (int p = 0; p < PB; p++) {
            int chunk = p * 256 + t;
            int r = chunk >> 2, ko = (chunk & 3) * 8;
            const short* gsrc = Bt + (size_t)(col0 + r) * K + k0 + ko;
            short* ldst = &Bs[(p * 256 + wave * 64) * 8];
            GL2LDS16(gsrc, ldst);
        }
        __syncthreads();
        short8 af[FM], bf[FN];
        #pragma unroll
        for (int mi = 0; mi < FM; mi++)
            af[mi] = *(const short8*)&As[(wm * HM + mi * 16 + l16) * BK + q * 8];
        #pragma unroll
        for (int ni = 0; ni < FN; ni++)
            bf[ni] = *(const short8*)&Bs[(wn * HN + ni * 16 + l16) * BK + q * 8];
        #pragma unroll
        for (int mi = 0; mi < FM; mi++)
            #pragma unroll
            for (int ni = 0; ni < FN; ni++)
                acc[mi][ni] = __builtin_amdgcn_mfma_f32_16x16x32_bf16(
                    af[mi], bf[ni], acc[mi][ni], 0, 0, 0);
        __syncthreads();
    }

    // epilogue: C/D layout col=lane&15, row=quad*4+reg
    #pragma unroll
    for (int ni = 0; ni < FN; ni++) {
        int cg = col0 + wn * HN + ni * 16 + l16;
        float bv = bias[cg];
        #pragma unroll
        for (int mi = 0; mi < FM; mi++) {
            #pragma unroll
            for (int r = 0; r < 4; r++) {
                int rg = row0 + wm * HM + mi * 16 + q * 4 + r;
                if (rg < M) {
                    float v = acc[mi][ni][r] + bv;
                    if (RES) v += res[(size_t)rg * CH + cg];
                    C[(size_t)rg * CH + cg] = v;
                    if (WBF) Cbf[(size_t)rg * CH + cg] = f2bf(v);
                }
            }
        }
    }
}

// ==================================================================== weight prep
// Wt[n*K+k] = bf16(W[k*256+n]) for 8 matrices (all have 256 output cols)
struct WPack {
    const float* src[8];
    short* dst[8];
    int K[8];
    int start[8];   // cumulative row offsets
};

__global__ __launch_bounds__(256) void wconv_kernel(WPack p)
{
    int gk = blockIdx.x;
    int m = 0;
    #pragma unroll
    for (int i = 1; i < 8; i++) if (gk >= p.start[i]) m = i;
    int k = gk - p.start[m];
    int t = threadIdx.x;
    p.dst[m][t * p.K[m] + k] = f2bf(p.src[m][k * 256 + t]);
}

__global__ void cast_bf_kernel(const float* __restrict__ src, short* __restrict__ dst, int n)
{
    int i = blockIdx.x * 256 + threadIdx.x;
    if (i < n) dst[i] = f2bf(src[i]);
}

// ==================================================================== e_in builder
// ein_bf[e,768] = bf16(relu(gn_768_g24(cat(x[row], x[col], eattr[e]))))
__global__ __launch_bounds__(256) void build_ein_kernel(
    const float* __restrict__ x, const float* __restrict__ eattr,
    const int* __restrict__ rowi, const int* __restrict__ coli,
    const float* __restrict__ gng, const float* __restrict__ gnb,
    short* __restrict__ ein, int E)
{
    __shared__ float sb[768];
    __shared__ float smu[32], srs[32];
    int e = blockIdx.x, t = threadIdx.x;
    int r = rowi[e], c = coli[e];
    float v0 = x[(size_t)r * CH + t];
    float v1 = x[(size_t)c * CH + t];
    float v2 = eattr[(size_t)e * CH + t];
    sb[t] = v0; sb[256 + t] = v1; sb[512 + t] = v2;
    __syncthreads();
    if (t < 32) {
        float s = 0.f, s2 = 0.f;
        const float* p = &sb[t * 24];
        #pragma unroll
        for (int i = 0; i < 24; i++) { float v = p[i]; s += v; s2 += v * v; }
        float m = s * (1.f / 24.f);
        float var = s2 * (1.f / 24.f) - m * m;
        smu[t] = m; srs[t] = rsqrtf(var + 1e-5f);
    }
    __syncthreads();
    size_t base = (size_t)e * 768;
    #pragma unroll
    for (int j = 0; j < 3; j++) {
        int pos = j * 256 + t;
        int g = pos / 24;
        float v = (j == 0) ? v0 : (j == 1) ? v1 : v2;
        v = fmaxf((v - smu[g]) * srs[g] * gng[pos] + gnb[pos], 0.f);
        ein[base + pos] = f2bf(v);
    }
}

// ==================================================================== GN(32x8)+ReLU -> bf16
__global__ __launch_bounds__(256) void gn_relu_cast_kernel(
    const float* __restrict__ h, const float* __restrict__ gamma,
    const float* __restrict__ beta, short* __restrict__ out, int rows)
{
    int t = threadIdx.x;
    int r = blockIdx.x * 8 + (t >> 5);
    int g = t & 31;
    if (r >= rows) return;
    size_t base = (size_t)r * CH + g * 8;
    float4 a = *(const float4*)&h[base];
    float4 b = *(const float4*)&h[base + 4];
    float s  = a.x + a.y + a.z + a.w + b.x + b.y + b.z + b.w;
    float s2 = a.x*a.x + a.y*a.y + a.z*a.z + a.w*a.w
             + b.x*b.x + b.y*b.y + b.z*b.z + b.w*b.w;
    float m = s * 0.125f;
    float var = s2 * 0.125f - m * m;
    float rsd = rsqrtf(var + 1e-5f);
    float4 g0 = *(const float4*)&gamma[g * 8];
    float4 g1 = *(const float4*)&gamma[g * 8 + 4];
    float4 b0 = *(const float4*)&beta[g * 8];
    float4 b1 = *(const float4*)&beta[g * 8 + 4];
    short8 o;
    o[0] = f2bf(fmaxf((a.x - m) * rsd * g0.x + b0.x, 0.f));
    o[1] = f2bf(fmaxf((a.y - m) * rsd * g0.y + b0.y, 0.f));
    o[2] = f2bf(fmaxf((a.z - m) * rsd * g0.z + b0.z, 0.f));
    o[3] = f2bf(fmaxf((a.w - m) * rsd * g0.w + b0.w, 0.f));
    o[4] = f2bf(fmaxf((b.x - m) * rsd * g1.x + b1.x, 0.f));
    o[5] = f2bf(fmaxf((b.y - m) * rsd * g1.y + b1.y, 0.f));
    o[6] = f2bf(fmaxf((b.z - m) * rsd * g1.z + b1.z, 0.f));
    o[7] = f2bf(fmaxf((b.w - m) * rsd * g1.w + b1.w, 0.f));
    *(short8*)&out[base] = o;
}

// ==================================================================== node concat (bf16)
// cat_bf[r, 0:256] = relu(gn(x[r])); cat_bf[r, 256:512] = gob[r]
__global__ __launch_bounds__(256) void node_cat_kernel(
    const float* __restrict__ x, const float* __restrict__ go,
    const float* __restrict__ gamma, const float* __restrict__ beta,
    short* __restrict__ cat, int N)
{
    int t = threadIdx.x;
    int r = blockIdx.x * 8 + (t >> 5);
    int g = t & 31;
    if (r >= N) return;
    size_t xb = (size_t)r * CH + g * 8;
    float4 a = *(const float4*)&x[xb];
    float4 b = *(const float4*)&x[xb + 4];
    float s  = a.x + a.y + a.z + a.w + b.x + b.y + b.z + b.w;
    float s2 = a.x*a.x + a.y*a.y + a.z*a.z + a.w*a.w
             + b.x*b.x + b.y*b.y + b.z*b.z + b.w*b.w;
    float m = s * 0.125f;
    float var = s2 * 0.125f - m * m;
    float rsd = rsqrtf(var + 1e-5f);
    float4 g0 = *(const float4*)&gamma[g * 8];
    float4 g1 = *(const float4*)&gamma[g * 8 + 4];
    float4 b0 = *(const float4*)&beta[g * 8];
    float4 b1 = *(const float4*)&beta[g * 8 + 4];
    size_t cb = (size_t)r * (2 * CH) + g * 8;
    short8 o;
    o[0] = f2bf(fmaxf((a.x - m) * rsd * g0.x + b0.x, 0.f));
    o[1] = f2bf(fmaxf((a.y - m) * rsd * g0.y + b0.y, 0.f));
    o[2] = f2bf(fmaxf((a.z - m) * rsd * g0.z + b0.z, 0.f));
    o[3] = f2bf(fmaxf((a.w - m) * rsd * g0.w + b0.w, 0.f));
    o[4] = f2bf(fmaxf((b.x - m) * rsd * g1.x + b1.x, 0.f));
    o[5] = f2bf(fmaxf((b.y - m) * rsd * g1.y + b1.y, 0.f));
    o[6] = f2bf(fmaxf((b.z - m) * rsd * g1.z + b1.z, 0.f));
    o[7] = f2bf(fmaxf((b.w - m) * rsd * g1.w + b1.w, 0.f));
    *(short8*)&cat[cb] = o;
    float4 c0 = *(const float4*)&go[xb];
    float4 c1 = *(const float4*)&go[xb + 4];
    short8 o2;
    o2[0] = f2bf(c0.x); o2[1] = f2bf(c0.y); o2[2] = f2bf(c0.z); o2[3] = f2bf(c0.w);
    o2[4] = f2bf(c1.x); o2[5] = f2bf(c1.y); o2[6] = f2bf(c1.z); o2[7] = f2bf(c1.w);
    *(short8*)&cat[cb + CH] = o2;
}

// ==================================================================== CSR build
__global__ void zero_kernel(int* __restrict__ counts, float* __restrict__ vbar, int N)
{
    int i = blockIdx.x * blockDim.x + threadIdx.x;
    if (i < N) counts[i] = 0;
    if (i < CH) vbar[i] = 0.f;
}

__global__ void count_kernel(const int* __restrict__ coli, int* __restrict__ counts, int E)
{
    int e = blockIdx.x * blockDim.x + threadIdx.x;
    if (e < E) atomicAdd(&counts[coli[e]], 1);
}

__global__ __launch_bounds__(1024) void scan_kernel(
    const int* __restrict__ counts, int* __restrict__ offsets,
    int* __restrict__ cursor, int N)
{
    __shared__ int s[1024];
    int t = threadIdx.x;
    int a = (2 * t     < N) ? counts[2 * t]     : 0;
    int b = (2 * t + 1 < N) ? counts[2 * t + 1] : 0;
    s[t] = a + b;
    __syncthreads();
    for (int off = 1; off < 1024; off <<= 1) {
        int v = (t >= off) ? s[t - off] : 0;
        __syncthreads();
        s[t] += v;
        __syncthreads();
    }
    int excl = (t > 0) ? s[t - 1] : 0;
    if (2 * t < N)     { offsets[2 * t]     = excl;     cursor[2 * t]     = excl; }
    if (2 * t + 1 < N) { offsets[2 * t + 1] = excl + a; cursor[2 * t + 1] = excl + a; }
    if (t == 1023) offsets[N] = s[1023];
}

__global__ void fill_kernel(const int* __restrict__ coli, int* __restrict__ cursor,
                            int* __restrict__ elist, int E)
{
    int e = blockIdx.x * blockDim.x + threadIdx.x;
    if (e < E) {
        int p = atomicAdd(&cursor[coli[e]], 1);
        elist[p] = e;
    }
}

__global__ __launch_bounds__(256) void vbar_kernel(
    const float* __restrict__ vb, float* __restrict__ vbar, int E)
{
    int t = threadIdx.x;
    int per = (E + gridDim.x - 1) / gridDim.x;
    int e0 = blockIdx.x * per;
    int e1 = e0 + per; if (e1 > E) e1 = E;
    float s = 0.f;
    for (int e = e0; e < e1; e++) s += vb[(size_t)e * CH + t];
    atomicAdd(&vbar[t], s);
}

// ==================================================================== attention
// block = node; wave = head (64 lanes = 64 head dims); output bf16 for Wo GEMM
__global__ __launch_bounds__(256) void attn_kernel(
    const float* __restrict__ qb, const float* __restrict__ kb,
    const float* __restrict__ vb, const int* __restrict__ offsets,
    const int* __restrict__ elist, const float* __restrict__ vbar,
    short* __restrict__ g_bf, int N, int E)
{
    int n = blockIdx.x;
    int c = threadIdx.x;
    float qv = qb[(size_t)n * CH + c];
    int s0 = offsets[n], s1 = offsets[n + 1];
    float m = -INFINITY, l = 0.f, num = 0.f;
    for (int idx = s0; idx < s1; idx++) {
        int e = elist[idx];
        float s = warp_sum64(qv * kb[(size_t)e * CH + c]) * 0.125f;  // 1/sqrt(64)
        float mn = fmaxf(m, s);
        float sc = __expf(m - mn);
        float p  = __expf(s - mn);
        l = l * sc + p;
        num = num * sc + p * vb[(size_t)e * CH + c];
        m = mn;
    }
    float out;
    if (s1 > s0) out = num / l;
    else         out = vbar[c] * (1.f / (float)E);  // 0-degree: uniform over all edges
    g_bf[(size_t)n * CH + c] = f2bf(out);
}

// ==================================================================== launch
extern "C" void kernel_launch(void* const* d_in, const int* in_sizes, int n_in,
                              void* d_out, int out_size, void* d_ws, size_t ws_size,
                              hipStream_t stream)
{
    const float* x       = (const float*)d_in[0];
    const int*   ei      = (const int*)d_in[1];
    const float* eattr   = (const float*)d_in[2];
    const float* gn_e1_g = (const float*)d_in[3];
    const float* gn_e1_b = (const float*)d_in[4];
    const float* We1     = (const float*)d_in[5];
    const float* be1     = (const float*)d_in[6];
    const float* gn_e2_g = (const float*)d_in[7];
    const float* gn_e2_b = (const float*)d_in[8];
    const float* We2     = (const float*)d_in[9];
    const float* be2     = (const float*)d_in[10];
    const float* gn_n_g  = (const float*)d_in[11];
    const float* gn_n_b  = (const float*)d_in[12];
    const float* Wq      = (const float*)d_in[13];
    const float* bq      = (const float*)d_in[14];
    const float* Wk      = (const float*)d_in[15];
    const float* bk      = (const float*)d_in[16];
    const float* Wv      = (const float*)d_in[17];
    const float* bv      = (const float*)d_in[18];
    const float* Wo      = (const float*)d_in[19];
    const float* bo      = (const float*)d_in[20];
    const float* Wn1     = (const float*)d_in[21];
    const float* bn1     = (const float*)d_in[22];
    const float* gn_n2_g = (const float*)d_in[23];
    const float* gn_n2_b = (const float*)d_in[24];
    const float* Wn2     = (const float*)d_in[25];
    const float* bn2     = (const float*)d_in[26];

    const int N = in_sizes[0] / CH;
    const int E = in_sizes[2] / CH;

    float* nout = (float*)d_out;                   // [N,256]
    float* eout = (float*)d_out + (size_t)N * CH;  // [E,256]

    // ---- workspace layout (all 16B-aligned sizes) ----
    char* base = (char*)d_ws;
    short* ein_bf = (short*)base;                  // [E,768] bf16
    float* vbuf   = (float*)base;                  // alias: [E,256] f32 (ein dead after GEMM1)
    base += (size_t)E * 768 * 2;
    float* h1   = (float*)base;                    // [E,256] f32
    float* kbuf = h1;                              // alias: h1 dead after gn_relu_cast
    base += (size_t)E * CH * 4;
    short* h2_bf  = (short*)base; base += (size_t)E * CH * 2;
    short* eo_bf  = (short*)base; base += (size_t)E * CH * 2;
    float* qbuf   = (float*)base; base += (size_t)N * CH * 4;
    short* g_bf   = (short*)base; base += (size_t)N * CH * 2;
    float* gob    = (float*)base; base += (size_t)N * CH * 4;
    short* cat_bf = (short*)base; base += (size_t)N * 2 * CH * 2;
    float* hn     = (float*)base; base += (size_t)N * CH * 4;
    short* hn_bf  = (short*)base; base += (size_t)N * CH * 2;
    short* x_bf   = (short*)base; base += (size_t)N * CH * 2;
    float* vbar   = (float*)base; base += CH * 4;
    const int wK[8] = {3 * CH, CH, CH, CH, CH, CH, 2 * CH, CH};
    short* Wt[8];
    for (int i = 0; i < 8; i++) { Wt[i] = (short*)base; base += (size_t)wK[i] * CH * 2; }
    int* counts  = (int*)base;
    int* offsets = counts + N;
    int* cursor  = offsets + (N + 1);
    int* elist   = cursor + N;

    const int* rowi = ei;
    const int* coli = ei + E;

    dim3 blk(256);
    dim3 gE(CH / 128, E / 128);            // (2, 125) edge GEMMs
    dim3 gN(CH / 64, (N + 63) / 64);       // (4, 32)  node GEMMs

    // ---- weight prep ----
    WPack wp;
    const float* wsrc[8] = {We1, We2, Wq, Wk, Wv, Wo, Wn1, Wn2};
    int acc = 0;
    for (int i = 0; i < 8; i++) {
        wp.src[i] = wsrc[i]; wp.dst[i] = Wt[i]; wp.K[i] = wK[i];
        wp.start[i] = acc; acc += wK[i];
    }
    wconv_kernel<<<acc, blk, 0, stream>>>(wp);
    cast_bf_kernel<<<(N * CH + 255) / 256, blk, 0, stream>>>(x, x_bf, N * CH);

    // ---- edge model ----
    build_ein_kernel<<<E, blk, 0, stream>>>(x, eattr, rowi, coli, gn_e1_g, gn_e1_b, ein_bf, E);
    mfma_gemm<128, 128, 0, 0><<<gE, blk, 0, stream>>>(ein_bf, Wt[0], be1, nullptr, h1, nullptr, E, 3 * CH);
    gn_relu_cast_kernel<<<E / 8, blk, 0, stream>>>(h1, gn_e2_g, gn_e2_b, h2_bf, E);
    mfma_gemm<128, 128, 1, 1><<<gE, blk, 0, stream>>>(h2_bf, Wt[1], be2, eattr, eout, eo_bf, E, CH);

    // ---- K/V/Q projections ----
    mfma_gemm<128, 128, 0, 0><<<gE, blk, 0, stream>>>(eo_bf, Wt[3], bk, nullptr, kbuf, nullptr, E, CH);
    mfma_gemm<128, 128, 0, 0><<<gE, blk, 0, stream>>>(eo_bf, Wt[4], bv, nullptr, vbuf, nullptr, E, CH);
    mfma_gemm<64, 64, 0, 0><<<gN, blk, 0, stream>>>(x_bf, Wt[2], bq, nullptr, qbuf, nullptr, N, CH);

    // ---- CSR + vbar ----
    zero_kernel<<<(N + 255) / 256, blk, 0, stream>>>(counts, vbar, N);
    count_kernel<<<(E + 255) / 256, blk, 0, stream>>>(coli, counts, E);
    scan_kernel<<<1, 1024, 0, stream>>>(counts, offsets, cursor, N);
    fill_kernel<<<(E + 255) / 256, blk, 0, stream>>>(coli, cursor, elist, E);
    vbar_kernel<<<64, blk, 0, stream>>>(vbuf, vbar, E);

    // ---- attention + output proj ----
    attn_kernel<<<N, blk, 0, stream>>>(qbuf, kbuf, vbuf, offsets, elist, vbar, g_bf, N, E);
    mfma_gemm<64, 64, 0, 0><<<gN, blk, 0, stream>>>(g_bf, Wt[5], bo, nullptr, gob, nullptr, N, CH);

    // ---- node MLP ----
    node_cat_kernel<<<(N + 7) / 8, blk, 0, stream>>>(x, gob, gn_n_g, gn_n_b, cat_bf, N);
    mfma_gemm<64, 64, 0, 0><<<gN, blk, 0, stream>>>(cat_bf, Wt[6], bn1, nullptr, hn, nullptr, N, 2 * CH);
    gn_relu_cast_kernel<<<(N + 7) / 8, blk, 0, stream>>>(hn, gn_n2_g, gn_n2_b, hn_bf, N);
    mfma_gemm<64, 64, 1, 0><<<gN, blk, 0, stream>>>(hn_bf, Wt[7], bn2, x, nout, nullptr, N, CH);
}

// Round 3
// 283.450 us; speedup vs baseline: 1.8038x; 1.2681x over previous
//
#include <hip/hip_runtime.h>
#include <hip/hip_bf16.h>
#include <stdint.h>
#include <math.h>

#define CH 256

typedef __attribute__((ext_vector_type(8)))  short short8;
typedef __attribute__((ext_vector_type(16))) short short16;
typedef __attribute__((ext_vector_type(4)))  float f32x4;

#define GL2LDS16(g, l) __builtin_amdgcn_global_load_lds(                       \
    (const __attribute__((address_space(1))) void*)(g),                        \
    (__attribute__((address_space(3))) void*)(l), 16, 0, 0)

__device__ inline short f2bf(float f) {
    __hip_bfloat16 h = __float2bfloat16(f);
    short s;
    __builtin_memcpy(&s, &h, 2);
    return s;
}

__device__ inline float warp_sum64(float v) {
    v += __shfl_xor(v, 32, 64);
    v += __shfl_xor(v, 16, 64);
    v += __shfl_xor(v, 8, 64);
    v += __shfl_xor(v, 4, 64);
    v += __shfl_xor(v, 2, 64);
    v += __shfl_xor(v, 1, 64);
    return v;
}

// ==================================================================== MFMA GEMM
// C[M,Nc] = A[M,K](bf16) x B (given as Bt[Nc,K] bf16) + bias (+res).
// m97 structure: BK=32, 4 waves (2x2), 16x16x32 bf16 MFMA, width-16
// global_load_lds staging, row-major [rows][32] LDS tiles.
template <int BM, int BN, int RES, int WBF>
__global__ __launch_bounds__(256) void mfma_gemm(
    const short* __restrict__ A, const short* __restrict__ Bt,
    const float* __restrict__ bias, const float* __restrict__ res,
    float* __restrict__ C, short* __restrict__ Cbf, int M, int K, int Nc)
{
    constexpr int BK = 32;
    constexpr int HM = BM / 2, HN = BN / 2;   // per-wave sub-tile (2x2 wave grid)
    constexpr int FM = HM / 16, FN = HN / 16; // 16x16 frags per wave
    constexpr int PA = (BM * BK) / (256 * 8); // staging passes (16B x 256thr = 4KB)
    constexpr int PB = (BN * BK) / (256 * 8);
    __shared__ short As[BM * BK];
    __shared__ short Bs[BN * BK];

    const int t = threadIdx.x;
    const int wave = t >> 6, lane = t & 63;
    const int q = lane >> 4, l16 = lane & 15;
    const int row0 = blockIdx.y * BM;
    const int col0 = blockIdx.x * BN;
    const int wm = wave & 1, wn = wave >> 1;

    f32x4 acc[FM][FN];
    #pragma unroll
    for (int i = 0; i < FM; i++)
        #pragma unroll
        for (int j = 0; j < FN; j++) acc[i][j] = (f32x4){0.f, 0.f, 0.f, 0.f};

    for (int k0 = 0; k0 < K; k0 += BK) {
        #pragma unroll
        for (int p = 0; p < PA; p++) {
            int chunk = p * 256 + t;
            int r = chunk >> 2, ko = (chunk & 3) * 8;
            int gr = row0 + r; if (gr >= M) gr = M - 1;
            const short* gsrc = A + (size_t)gr * K + k0 + ko;
            short* ldst = &As[(p * 256 + wave * 64) * 8];  // wave-uniform base
            GL2LDS16(gsrc, ldst);
        }
        #pragma unroll
        for (int p = 0; p < PB; p++) {
            int chunk = p * 256 + t;
            int r = chunk >> 2, ko = (chunk & 3) * 8;
            const short* gsrc = Bt + (size_t)(col0 + r) * K + k0 + ko;
            short* ldst = &Bs[(p * 256 + wave * 64) * 8];
            GL2LDS16(gsrc, ldst);
        }
        __syncthreads();
        short8 af[FM], bf[FN];
        #pragma unroll
        for (int mi = 0; mi < FM; mi++)
            af[mi] = *(const short8*)&As[(wm * HM + mi * 16 + l16) * BK + q * 8];
        #pragma unroll
        for (int ni = 0; ni < FN; ni++)
            bf[ni] = *(const short8*)&Bs[(wn * HN + ni * 16 + l16) * BK + q * 8];
        #pragma unroll
        for (int mi = 0; mi < FM; mi++)
            #pragma unroll
            for (int ni = 0; ni < FN; ni++)
                acc[mi][ni] = __builtin_amdgcn_mfma_f32_16x16x32_bf16(
                    af[mi], bf[ni], acc[mi][ni], 0, 0, 0);
        __syncthreads();
    }

    // epilogue: C/D layout col=lane&15, row=quad*4+reg
    #pragma unroll
    for (int ni = 0; ni < FN; ni++) {
        int cg = col0 + wn * HN + ni * 16 + l16;
        float bv = bias[cg];
        #pragma unroll
        for (int mi = 0; mi < FM; mi++) {
            #pragma unroll
            for (int r = 0; r < 4; r++) {
                int rg = row0 + wm * HM + mi * 16 + q * 4 + r;
                if (rg < M) {
                    float v = acc[mi][ni][r] + bv;
                    if (RES) v += res[(size_t)rg * Nc + cg];
                    C[(size_t)rg * Nc + cg] = v;
                    if (WBF) Cbf[(size_t)rg * Nc + cg] = f2bf(v);
                }
            }
        }
    }
}

// ==================================================================== weight prep
// dst[n*K + k] = bf16(src[k*256 + n]); block = 16 consecutive k rows of one matrix
struct WPack {
    const float* src[8];
    short* dst[8];
    int K[8];
    int start[8];   // cumulative 16-row-chunk offsets
};

__global__ __launch_bounds__(256) void wconv_kernel(WPack p)
{
    int gk = blockIdx.x;
    int m = 0;
    #pragma unroll
    for (int i = 1; i < 8; i++) if (gk >= p.start[i]) m = i;
    int k0 = (gk - p.start[m]) * 16;
    int t = threadIdx.x;
    const float* src = p.src[m];
    short16 o;
    #pragma unroll
    for (int j = 0; j < 16; j++) o[j] = f2bf(src[(size_t)(k0 + j) * 256 + t]);
    *(short16*)(p.dst[m] + (size_t)t * p.K[m] + k0) = o;
}

// prep: cast x -> bf16, zero vbar, build bkv = [bk | bv]
__global__ __launch_bounds__(256) void prep_kernel(
    const float* __restrict__ x, short* __restrict__ x_bf, int n,
    float* __restrict__ vbar, const float* __restrict__ bk,
    const float* __restrict__ bv, float* __restrict__ bkv)
{
    int i = blockIdx.x * 256 + threadIdx.x;
    if (i < n) x_bf[i] = f2bf(x[i]);
    if (blockIdx.x == 0) {
        int t = threadIdx.x;
        vbar[t] = 0.f;
        bkv[t] = bk[t];
        bkv[256 + t] = bv[t];
    }
}

// ==================================================================== e_in builder
// ein_bf[e,768] = bf16(relu(gn_768_g24(cat(x[row], x[col], eattr[e]))))
__global__ __launch_bounds__(256) void build_ein_kernel(
    const float* __restrict__ x, const float* __restrict__ eattr,
    const int* __restrict__ rowi, const int* __restrict__ coli,
    const float* __restrict__ gng, const float* __restrict__ gnb,
    short* __restrict__ ein, int E)
{
    __shared__ float sb[768];
    __shared__ float smu[32], srs[32];
    int e = blockIdx.x, t = threadIdx.x;
    int r = rowi[e], c = coli[e];
    float v0 = x[(size_t)r * CH + t];
    float v1 = x[(size_t)c * CH + t];
    float v2 = eattr[(size_t)e * CH + t];
    sb[t] = v0; sb[256 + t] = v1; sb[512 + t] = v2;
    __syncthreads();
    if (t < 32) {
        float s = 0.f, s2 = 0.f;
        const float* p = &sb[t * 24];
        #pragma unroll
        for (int i = 0; i < 24; i++) { float v = p[i]; s += v; s2 += v * v; }
        float m = s * (1.f / 24.f);
        float var = s2 * (1.f / 24.f) - m * m;
        smu[t] = m; srs[t] = rsqrtf(var + 1e-5f);
    }
    __syncthreads();
    size_t base = (size_t)e * 768;
    #pragma unroll
    for (int j = 0; j < 3; j++) {
        int pos = j * 256 + t;
        int g = pos / 24;
        float v = (j == 0) ? v0 : (j == 1) ? v1 : v2;
        v = fmaxf((v - smu[g]) * srs[g] * gng[pos] + gnb[pos], 0.f);
        ein[base + pos] = f2bf(v);
    }
}

// ==================================================================== GN(32x8)+ReLU -> bf16
__global__ __launch_bounds__(256) void gn_relu_cast_kernel(
    const float* __restrict__ h, const float* __restrict__ gamma,
    const float* __restrict__ beta, short* __restrict__ out, int rows)
{
    int t = threadIdx.x;
    int r = blockIdx.x * 8 + (t >> 5);
    int g = t & 31;
    if (r >= rows) return;
    size_t base = (size_t)r * CH + g * 8;
    float4 a = *(const float4*)&h[base];
    float4 b = *(const float4*)&h[base + 4];
    float s  = a.x + a.y + a.z + a.w + b.x + b.y + b.z + b.w;
    float s2 = a.x*a.x + a.y*a.y + a.z*a.z + a.w*a.w
             + b.x*b.x + b.y*b.y + b.z*b.z + b.w*b.w;
    float m = s * 0.125f;
    float var = s2 * 0.125f - m * m;
    float rsd = rsqrtf(var + 1e-5f);
    float4 g0 = *(const float4*)&gamma[g * 8];
    float4 g1 = *(const float4*)&gamma[g * 8 + 4];
    float4 b0 = *(const float4*)&beta[g * 8];
    float4 b1 = *(const float4*)&beta[g * 8 + 4];
    short8 o;
    o[0] = f2bf(fmaxf((a.x - m) * rsd * g0.x + b0.x, 0.f));
    o[1] = f2bf(fmaxf((a.y - m) * rsd * g0.y + b0.y, 0.f));
    o[2] = f2bf(fmaxf((a.z - m) * rsd * g0.z + b0.z, 0.f));
    o[3] = f2bf(fmaxf((a.w - m) * rsd * g0.w + b0.w, 0.f));
    o[4] = f2bf(fmaxf((b.x - m) * rsd * g1.x + b1.x, 0.f));
    o[5] = f2bf(fmaxf((b.y - m) * rsd * g1.y + b1.y, 0.f));
    o[6] = f2bf(fmaxf((b.z - m) * rsd * g1.z + b1.z, 0.f));
    o[7] = f2bf(fmaxf((b.w - m) * rsd * g1.w + b1.w, 0.f));
    *(short8*)&out[base] = o;
}

// ==================================================================== node concat (bf16)
__global__ __launch_bounds__(256) void node_cat_kernel(
    const float* __restrict__ x, const float* __restrict__ go,
    const float* __restrict__ gamma, const float* __restrict__ beta,
    short* __restrict__ cat, int N)
{
    int t = threadIdx.x;
    int r = blockIdx.x * 8 + (t >> 5);
    int g = t & 31;
    if (r >= N) return;
    size_t xb = (size_t)r * CH + g * 8;
    float4 a = *(const float4*)&x[xb];
    float4 b = *(const float4*)&x[xb + 4];
    float s  = a.x + a.y + a.z + a.w + b.x + b.y + b.z + b.w;
    float s2 = a.x*a.x + a.y*a.y + a.z*a.z + a.w*a.w
             + b.x*b.x + b.y*b.y + b.z*b.z + b.w*b.w;
    float m = s * 0.125f;
    float var = s2 * 0.125f - m * m;
    float rsd = rsqrtf(var + 1e-5f);
    float4 g0 = *(const float4*)&gamma[g * 8];
    float4 g1 = *(const float4*)&gamma[g * 8 + 4];
    float4 b0 = *(const float4*)&beta[g * 8];
    float4 b1 = *(const float4*)&beta[g * 8 + 4];
    size_t cb = (size_t)r * (2 * CH) + g * 8;
    short8 o;
    o[0] = f2bf(fmaxf((a.x - m) * rsd * g0.x + b0.x, 0.f));
    o[1] = f2bf(fmaxf((a.y - m) * rsd * g0.y + b0.y, 0.f));
    o[2] = f2bf(fmaxf((a.z - m) * rsd * g0.z + b0.z, 0.f));
    o[3] = f2bf(fmaxf((a.w - m) * rsd * g0.w + b0.w, 0.f));
    o[4] = f2bf(fmaxf((b.x - m) * rsd * g1.x + b1.x, 0.f));
    o[5] = f2bf(fmaxf((b.y - m) * rsd * g1.y + b1.y, 0.f));
    o[6] = f2bf(fmaxf((b.z - m) * rsd * g1.z + b1.z, 0.f));
    o[7] = f2bf(fmaxf((b.w - m) * rsd * g1.w + b1.w, 0.f));
    *(short8*)&cat[cb] = o;
    float4 c0 = *(const float4*)&go[xb];
    float4 c1 = *(const float4*)&go[xb + 4];
    short8 o2;
    o2[0] = f2bf(c0.x); o2[1] = f2bf(c0.y); o2[2] = f2bf(c0.z); o2[3] = f2bf(c0.w);
    o2[4] = f2bf(c1.x); o2[5] = f2bf(c1.y); o2[6] = f2bf(c1.z); o2[7] = f2bf(c1.w);
    *(short8*)&cat[cb + CH] = o2;
}

// ==================================================================== CSR build, single block
// counts -> scan -> fill, all in LDS (N <= 2048)
__global__ __launch_bounds__(1024) void csr_kernel(
    const int* __restrict__ coli, int* __restrict__ offsets,
    int* __restrict__ elist, int N, int E)
{
    __shared__ int cnt[2048];
    __shared__ int s[1024];
    int t = threadIdx.x;
    cnt[t] = 0; cnt[1024 + t] = 0;
    __syncthreads();
    for (int e = t; e < E; e += 1024) atomicAdd(&cnt[coli[e]], 1);
    __syncthreads();
    int a = (2 * t     < N) ? cnt[2 * t]     : 0;
    int b = (2 * t + 1 < N) ? cnt[2 * t + 1] : 0;
    s[t] = a + b;
    __syncthreads();
    for (int off = 1; off < 1024; off <<= 1) {
        int v = (t >= off) ? s[t - off] : 0;
        __syncthreads();
        s[t] += v;
        __syncthreads();
    }
    int excl = (t > 0) ? s[t - 1] : 0;
    if (2 * t < N)     { offsets[2 * t]     = excl;     cnt[2 * t]     = excl; }
    if (2 * t + 1 < N) { offsets[2 * t + 1] = excl + a; cnt[2 * t + 1] = excl + a; }
    if (t == 1023) offsets[N] = s[1023];
    __syncthreads();
    for (int e = t; e < E; e += 1024) {
        int p = atomicAdd(&cnt[coli[e]], 1);
        elist[p] = e;
    }
}

// ==================================================================== vbar (column mean of V)
// 512 blocks x 256 threads; thread t owns channel t; unrolled independent loads
__global__ __launch_bounds__(256) void vbar_kernel(
    const float* __restrict__ kv, float* __restrict__ vbar, int E)
{
    int t = threadIdx.x;
    int per = (E + gridDim.x - 1) / gridDim.x;
    int e0 = blockIdx.x * per;
    int e1 = e0 + per; if (e1 > E) e1 = E;
    float s = 0.f;
    #pragma unroll 4
    for (int e = e0; e < e1; e++) s += kv[(size_t)e * 512 + 256 + t];
    atomicAdd(&vbar[t], s);
}

// ==================================================================== attention
// block = node; wave = head (64 lanes = head dims); 1-deep K/V prefetch
__global__ __launch_bounds__(256) void attn_kernel(
    const float* __restrict__ qb, const float* __restrict__ kv,
    const int* __restrict__ offsets, const int* __restrict__ elist,
    const float* __restrict__ vbar, short* __restrict__ g_bf, int N, int E)
{
    int n = blockIdx.x;
    int c = threadIdx.x;
    float qv = qb[(size_t)n * CH + c];
    int s0 = offsets[n], s1 = offsets[n + 1];
    float out;
    if (s1 > s0) {
        float m = -INFINITY, l = 0.f, num = 0.f;
        int e = elist[s0];
        float kc = kv[(size_t)e * 512 + c];
        float vc = kv[(size_t)e * 512 + 256 + c];
        for (int idx = s0; idx < s1; idx++) {
            float kcur = kc, vcur = vc;
            if (idx + 1 < s1) {
                int e2 = elist[idx + 1];
                kc = kv[(size_t)e2 * 512 + c];
                vc = kv[(size_t)e2 * 512 + 256 + c];
            }
            float sdot = warp_sum64(qv * kcur) * 0.125f;  // 1/sqrt(64)
            float mn = fmaxf(m, sdot);
            float sc = __expf(m - mn);
            float p  = __expf(sdot - mn);
            l = l * sc + p;
            num = num * sc + p * vcur;
            m = mn;
        }
        out = num / l;
    } else {
        out = vbar[c] * (1.f / (float)E);  // 0-degree: uniform softmax over all edges
    }
    g_bf[(size_t)n * CH + c] = f2bf(out);
}

// ==================================================================== launch
extern "C" void kernel_launch(void* const* d_in, const int* in_sizes, int n_in,
                              void* d_out, int out_size, void* d_ws, size_t ws_size,
                              hipStream_t stream)
{
    const float* x       = (const float*)d_in[0];
    const int*   ei      = (const int*)d_in[1];
    const float* eattr   = (const float*)d_in[2];
    const float* gn_e1_g = (const float*)d_in[3];
    const float* gn_e1_b = (const float*)d_in[4];
    const float* We1     = (const float*)d_in[5];
    const float* be1     = (const float*)d_in[6];
    const float* gn_e2_g = (const float*)d_in[7];
    const float* gn_e2_b = (const float*)d_in[8];
    const float* We2     = (const float*)d_in[9];
    const float* be2     = (const float*)d_in[10];
    const float* gn_n_g  = (const float*)d_in[11];
    const float* gn_n_b  = (const float*)d_in[12];
    const float* Wq      = (const float*)d_in[13];
    const float* bq      = (const float*)d_in[14];
    const float* Wk      = (const float*)d_in[15];
    const float* bk      = (const float*)d_in[16];
    const float* Wv      = (const float*)d_in[17];
    const float* bv      = (const float*)d_in[18];
    const float* Wo      = (const float*)d_in[19];
    const float* bo      = (const float*)d_in[20];
    const float* Wn1     = (const float*)d_in[21];
    const float* bn1     = (const float*)d_in[22];
    const float* gn_n2_g = (const float*)d_in[23];
    const float* gn_n2_b = (const float*)d_in[24];
    const float* Wn2     = (const float*)d_in[25];
    const float* bn2     = (const float*)d_in[26];

    const int N = in_sizes[0] / CH;
    const int E = in_sizes[2] / CH;

    float* nout = (float*)d_out;                   // [N,256]
    float* eout = (float*)d_out + (size_t)N * CH;  // [E,256]

    // ---- workspace layout ----
    // [0, 24.58M)  ein_bf (dead after GEMM1)
    // [24.58M, 40.96M) h1 (dead after gn_relu_cast)
    // kvbuf [E,512] f32 (32.77M) aliases [0, 32.77M) -- written after both die
    char* base = (char*)d_ws;
    short* ein_bf = (short*)base;
    float* kvbuf  = (float*)base;
    float* h1     = (float*)(base + (size_t)E * 768 * 2);
    base += (size_t)E * 768 * 2 + (size_t)E * CH * 4;   // 40.96M span
    short* h2_bf  = (short*)base; base += (size_t)E * CH * 2;
    short* eo_bf  = (short*)base; base += (size_t)E * CH * 2;
    float* qbuf   = (float*)base; base += (size_t)N * CH * 4;
    short* g_bf   = (short*)base; base += (size_t)N * CH * 2;
    float* gob    = (float*)base; base += (size_t)N * CH * 4;
    short* cat_bf = (short*)base; base += (size_t)N * 2 * CH * 2;
    float* hn     = (float*)base; base += (size_t)N * CH * 4;
    short* hn_bf  = (short*)base; base += (size_t)N * CH * 2;
    short* x_bf   = (short*)base; base += (size_t)N * CH * 2;
    float* vbar   = (float*)base; base += 1024;
    float* bkv    = (float*)base; base += 2048;
    // weights: We1t(768), We2t(256), Wqt(256), Wkvt(512), Wot(256), Wn1t(512), Wn2t(256)
    short* We1t = (short*)base; base += (size_t)768 * 256 * 2;
    short* We2t = (short*)base; base += (size_t)256 * 256 * 2;
    short* Wqt  = (short*)base; base += (size_t)256 * 256 * 2;
    short* Wkvt = (short*)base; base += (size_t)512 * 256 * 2;
    short* Wot  = (short*)base; base += (size_t)256 * 256 * 2;
    short* Wn1t = (short*)base; base += (size_t)512 * 256 * 2;
    short* Wn2t = (short*)base; base += (size_t)256 * 256 * 2;
    int* offsets = (int*)base;
    int* elist   = offsets + (N + 1) + 3;   // keep 16B-ish alignment slack

    const int* rowi = ei;
    const int* coli = ei + E;

    dim3 blk(256);
    dim3 gE(CH / 64, E / 128);       // (4,125)=500 blocks, 128x64 tiles
    dim3 gKV(512 / 64, E / 128);     // (8,125)=1000 blocks
    dim3 gN(CH / 64, (N + 63) / 64); // (4,32)=128 blocks, 64x64 tiles

    // ---- weight prep (16-row chunks) ----
    WPack wp;
    const float* wsrc[8] = {We1, We2, Wq, Wk, Wv, Wo, Wn1, Wn2};
    short* wdst[8] = {We1t, We2t, Wqt, Wkvt, Wkvt + (size_t)256 * 256, Wot, Wn1t, Wn2t};
    const int wKd[8] = {768, 256, 256, 256, 256, 256, 512, 256};
    int acc = 0;
    for (int i = 0; i < 8; i++) {
        wp.src[i] = wsrc[i]; wp.dst[i] = wdst[i]; wp.K[i] = wKd[i];
        wp.start[i] = acc; acc += wKd[i] / 16;
    }
    wconv_kernel<<<acc, blk, 0, stream>>>(wp);
    prep_kernel<<<(N * CH + 255) / 256, blk, 0, stream>>>(x, x_bf, N * CH, vbar, bk, bv, bkv);
    csr_kernel<<<1, 1024, 0, stream>>>(coli, offsets, elist, N, E);

    // ---- edge model ----
    build_ein_kernel<<<E, blk, 0, stream>>>(x, eattr, rowi, coli, gn_e1_g, gn_e1_b, ein_bf, E);
    mfma_gemm<128, 64, 0, 0><<<gE, blk, 0, stream>>>(ein_bf, We1t, be1, nullptr, h1, nullptr, E, 3 * CH, CH);
    gn_relu_cast_kernel<<<E / 8, blk, 0, stream>>>(h1, gn_e2_g, gn_e2_b, h2_bf, E);
    mfma_gemm<128, 64, 1, 1><<<gE, blk, 0, stream>>>(h2_bf, We2t, be2, eattr, eout, eo_bf, E, CH, CH);

    // ---- projections: fused KV [E,512], Q [N,256] ----
    mfma_gemm<128, 64, 0, 0><<<gKV, blk, 0, stream>>>(eo_bf, Wkvt, bkv, nullptr, kvbuf, nullptr, E, CH, 512);
    mfma_gemm<64, 64, 0, 0><<<gN, blk, 0, stream>>>(x_bf, Wqt, bq, nullptr, qbuf, nullptr, N, CH, CH);

    // ---- vbar + attention + output proj ----
    vbar_kernel<<<512, blk, 0, stream>>>(kvbuf, vbar, E);
    attn_kernel<<<N, blk, 0, stream>>>(qbuf, kvbuf, offsets, elist, vbar, g_bf, N, E);
    mfma_gemm<64, 64, 0, 0><<<gN, blk, 0, stream>>>(g_bf, Wot, bo, nullptr, gob, nullptr, N, CH, CH);

    // ---- node MLP ----
    node_cat_kernel<<<(N + 7) / 8, blk, 0, stream>>>(x, gob, gn_n_g, gn_n_b, cat_bf, N);
    mfma_gemm<64, 64, 0, 0><<<gN, blk, 0, stream>>>(cat_bf, Wn1t, bn1, nullptr, hn, nullptr, N, 2 * CH, CH);
    gn_relu_cast_kernel<<<(N + 7) / 8, blk, 0, stream>>>(hn, gn_n2_g, gn_n2_b, hn_bf, N);
    mfma_gemm<64, 64, 1, 0><<<gN, blk, 0, stream>>>(hn_bf, Wn2t, bn2, x, nout, nullptr, N, CH, CH);
}

// Round 4
// 277.619 us; speedup vs baseline: 1.8417x; 1.0210x over previous
//
#include <hip/hip_runtime.h>
#include <hip/hip_bf16.h>
#include <stdint.h>
#include <math.h>

#define CH 256

typedef __attribute__((ext_vector_type(8)))  short short8;
typedef __attribute__((ext_vector_type(16))) short short16;
typedef __attribute__((ext_vector_type(4)))  float f32x4;

#define GL2LDS16(g, l) __builtin_amdgcn_global_load_lds(                       \
    (const __attribute__((address_space(1))) void*)(g),                        \
    (__attribute__((address_space(3))) void*)(l), 16, 0, 0)

__device__ inline short f2bf(float f) {
    __hip_bfloat16 h = __float2bfloat16(f);
    short s;
    __builtin_memcpy(&s, &h, 2);
    return s;
}

__device__ inline float warp_sum64(float v) {
    v += __shfl_xor(v, 32, 64);
    v += __shfl_xor(v, 16, 64);
    v += __shfl_xor(v, 8, 64);
    v += __shfl_xor(v, 4, 64);
    v += __shfl_xor(v, 2, 64);
    v += __shfl_xor(v, 1, 64);
    return v;
}

// ==================================================================== MFMA GEMM
// C = A[M,K](bf16) x Bt[Nc,K](bf16) + bias, with fused epilogues.
// EPI 0: f32 out to C (opt) + res (opt) + bf16 dup to Cbf (opt)
// EPI 1: GroupNorm(groups of 8 cols)+ReLU -> bf16 to Cbf only
// VB 1:  atomically accumulate column sums of cols >=256 into vbar (KV path)
// Output addressing: ptr[(rg*ldc) + coff + cg] for both C and Cbf.
template <int BM, int BN, int EPI, int VB>
__global__ __launch_bounds__(256) void mfma_gemm(
    const short* __restrict__ A, const short* __restrict__ Bt,
    const float* __restrict__ bias, const float* __restrict__ res,
    float* __restrict__ C, short* __restrict__ Cbf,
    const float* __restrict__ gamma, const float* __restrict__ beta,
    float* __restrict__ vbar,
    int M, int K, int Nc, int ldc, int coff)
{
    constexpr int BK = 32;
    constexpr int HM = BM / 2, HN = BN / 2;   // 2x2 wave grid
    constexpr int FM = HM / 16, FN = HN / 16;
    constexpr int PA = (BM * BK) / (256 * 8);
    constexpr int PB = (BN * BK) / (256 * 8);
    __shared__ short As[BM * BK];
    __shared__ short Bs[BN * BK];

    const int t = threadIdx.x;
    const int wave = t >> 6, lane = t & 63;
    const int q = lane >> 4, l16 = lane & 15;
    const int row0 = blockIdx.y * BM;
    const int col0 = blockIdx.x * BN;
    const int wm = wave & 1, wn = wave >> 1;

    f32x4 acc[FM][FN];
    #pragma unroll
    for (int i = 0; i < FM; i++)
        #pragma unroll
        for (int j = 0; j < FN; j++) acc[i][j] = (f32x4){0.f, 0.f, 0.f, 0.f};

    for (int k0 = 0; k0 < K; k0 += BK) {
        #pragma unroll
        for (int p = 0; p < PA; p++) {
            int chunk = p * 256 + t;
            int r = chunk >> 2, ko = (chunk & 3) * 8;
            int gr = row0 + r; if (gr >= M) gr = M - 1;
            const short* gsrc = A + (size_t)gr * K + k0 + ko;
            short* ldst = &As[(p * 256 + wave * 64) * 8];
            GL2LDS16(gsrc, ldst);
        }
        #pragma unroll
        for (int p = 0; p < PB; p++) {
            int chunk = p * 256 + t;
            int r = chunk >> 2, ko = (chunk & 3) * 8;
            const short* gsrc = Bt + (size_t)(col0 + r) * K + k0 + ko;
            short* ldst = &Bs[(p * 256 + wave * 64) * 8];
            GL2LDS16(gsrc, ldst);
        }
        __syncthreads();
        short8 af[FM], bf[FN];
        #pragma unroll
        for (int mi = 0; mi < FM; mi++)
            af[mi] = *(const short8*)&As[(wm * HM + mi * 16 + l16) * BK + q * 8];
        #pragma unroll
        for (int ni = 0; ni < FN; ni++)
            bf[ni] = *(const short8*)&Bs[(wn * HN + ni * 16 + l16) * BK + q * 8];
        #pragma unroll
        for (int mi = 0; mi < FM; mi++)
            #pragma unroll
            for (int ni = 0; ni < FN; ni++)
                acc[mi][ni] = __builtin_amdgcn_mfma_f32_16x16x32_bf16(
                    af[mi], bf[ni], acc[mi][ni], 0, 0, 0);
        __syncthreads();
    }

    // ---- epilogue; C/D layout: col = l16, row = q*4 + r ----
    #pragma unroll
    for (int ni = 0; ni < FN; ni++) {
        int cg = col0 + wn * HN + ni * 16 + l16;
        float bv = bias[cg];
        if constexpr (EPI == 1) {
            float ga = gamma[cg], be = beta[cg];
            #pragma unroll
            for (int mi = 0; mi < FM; mi++) {
                #pragma unroll
                for (int r = 0; r < 4; r++) {
                    float v = acc[mi][ni][r] + bv;
                    float s = v, sq = v * v;
                    s += __shfl_xor(s, 1, 64);  sq += __shfl_xor(sq, 1, 64);
                    s += __shfl_xor(s, 2, 64);  sq += __shfl_xor(sq, 2, 64);
                    s += __shfl_xor(s, 4, 64);  sq += __shfl_xor(sq, 4, 64);
                    float mean = s * 0.125f;
                    float var = sq * 0.125f - mean * mean;
                    float o = fmaxf((v - mean) * rsqrtf(var + 1e-5f) * ga + be, 0.f);
                    int rg = row0 + wm * HM + mi * 16 + q * 4 + r;
                    if (rg < M) Cbf[(size_t)rg * ldc + coff + cg] = f2bf(o);
                }
            }
        } else {
            #pragma unroll
            for (int mi = 0; mi < FM; mi++) {
                #pragma unroll
                for (int r = 0; r < 4; r++) {
                    int rg = row0 + wm * HM + mi * 16 + q * 4 + r;
                    if (rg < M) {
                        float v = acc[mi][ni][r] + bv;
                        if (res) v += res[(size_t)rg * ldc + coff + cg];
                        if (C)   C[(size_t)rg * ldc + coff + cg] = v;
                        if (Cbf) Cbf[(size_t)rg * ldc + coff + cg] = f2bf(v);
                    }
                }
            }
            if constexpr (VB) {
                if (cg >= 256) {   // V half of the fused KV output
                    float part = 0.f;
                    #pragma unroll
                    for (int mi = 0; mi < FM; mi++)
                        #pragma unroll
                        for (int r = 0; r < 4; r++) {
                            int rg = row0 + wm * HM + mi * 16 + q * 4 + r;
                            if (rg < M) part += acc[mi][ni][r] + bv;
                        }
                    part += __shfl_xor(part, 16, 64);
                    part += __shfl_xor(part, 32, 64);
                    if (q == 0) atomicAdd(&vbar[cg - 256], part);
                }
            }
        }
    }
}

// ==================================================================== weight prep
// dst[n*LD + k] = bf16(src[k*256 + n]); block = 16 consecutive k rows
struct WPack {
    const float* src[8];
    short* dst[8];
    int K[8];       // row stride of dst (= K of that GEMM)
    int start[8];   // cumulative 16-row-chunk offsets
};

__global__ __launch_bounds__(256) void wconv_kernel(WPack p)
{
    int gk = blockIdx.x;
    int m = 0;
    #pragma unroll
    for (int i = 1; i < 8; i++) if (gk >= p.start[i]) m = i;
    int k0 = (gk - p.start[m]) * 16;
    int t = threadIdx.x;
    const float* src = p.src[m];
    short16 o;
    #pragma unroll
    for (int j = 0; j < 16; j++) o[j] = f2bf(src[(size_t)(k0 + j) * 256 + t]);
    *(short16*)(p.dst[m] + (size_t)t * p.K[m] + k0) = o;
}

// ==================================================================== prep
// x_bf = bf16(x); cat_bf[:, :256] = bf16(relu(gn_n(x))); vbar=0; bkv=[bk|bv]
__global__ __launch_bounds__(256) void prep_kernel(
    const float* __restrict__ x, short* __restrict__ x_bf,
    short* __restrict__ cat_bf,
    const float* __restrict__ gng, const float* __restrict__ gnb,
    float* __restrict__ vbar, const float* __restrict__ bk,
    const float* __restrict__ bv, float* __restrict__ bkv, int N)
{
    int t = threadIdx.x;
    if (blockIdx.x == 0) {
        vbar[t] = 0.f;
        bkv[t] = bk[t];
        bkv[256 + t] = bv[t];
    }
    int r = blockIdx.x * 8 + (t >> 5);
    int g = t & 31;
    if (r >= N) return;
    size_t xb = (size_t)r * CH + g * 8;
    float4 a = *(const float4*)&x[xb];
    float4 b = *(const float4*)&x[xb + 4];
    short8 xr;
    xr[0] = f2bf(a.x); xr[1] = f2bf(a.y); xr[2] = f2bf(a.z); xr[3] = f2bf(a.w);
    xr[4] = f2bf(b.x); xr[5] = f2bf(b.y); xr[6] = f2bf(b.z); xr[7] = f2bf(b.w);
    *(short8*)&x_bf[xb] = xr;
    float s  = a.x + a.y + a.z + a.w + b.x + b.y + b.z + b.w;
    float s2 = a.x*a.x + a.y*a.y + a.z*a.z + a.w*a.w
             + b.x*b.x + b.y*b.y + b.z*b.z + b.w*b.w;
    float m = s * 0.125f;
    float var = s2 * 0.125f - m * m;
    float rsd = rsqrtf(var + 1e-5f);
    float4 g0 = *(const float4*)&gng[g * 8];
    float4 g1 = *(const float4*)&gng[g * 8 + 4];
    float4 b0 = *(const float4*)&gnb[g * 8];
    float4 b1 = *(const float4*)&gnb[g * 8 + 4];
    short8 o;
    o[0] = f2bf(fmaxf((a.x - m) * rsd * g0.x + b0.x, 0.f));
    o[1] = f2bf(fmaxf((a.y - m) * rsd * g0.y + b0.y, 0.f));
    o[2] = f2bf(fmaxf((a.z - m) * rsd * g0.z + b0.z, 0.f));
    o[3] = f2bf(fmaxf((a.w - m) * rsd * g0.w + b0.w, 0.f));
    o[4] = f2bf(fmaxf((b.x - m) * rsd * g1.x + b1.x, 0.f));
    o[5] = f2bf(fmaxf((b.y - m) * rsd * g1.y + b1.y, 0.f));
    o[6] = f2bf(fmaxf((b.z - m) * rsd * g1.z + b1.z, 0.f));
    o[7] = f2bf(fmaxf((b.w - m) * rsd * g1.w + b1.w, 0.f));
    *(short8*)&cat_bf[(size_t)r * (2 * CH) + g * 8] = o;
}

// ==================================================================== e_in builder
__global__ __launch_bounds__(256) void build_ein_kernel(
    const float* __restrict__ x, const float* __restrict__ eattr,
    const int* __restrict__ rowi, const int* __restrict__ coli,
    const float* __restrict__ gng, const float* __restrict__ gnb,
    short* __restrict__ ein, int E)
{
    __shared__ float sb[768];
    __shared__ float smu[32], srs[32];
    int e = blockIdx.x, t = threadIdx.x;
    int r = rowi[e], c = coli[e];
    float v0 = x[(size_t)r * CH + t];
    float v1 = x[(size_t)c * CH + t];
    float v2 = eattr[(size_t)e * CH + t];
    sb[t] = v0; sb[256 + t] = v1; sb[512 + t] = v2;
    __syncthreads();
    if (t < 32) {
        float s = 0.f, s2 = 0.f;
        const float* p = &sb[t * 24];
        #pragma unroll
        for (int i = 0; i < 24; i++) { float v = p[i]; s += v; s2 += v * v; }
        float m = s * (1.f / 24.f);
        float var = s2 * (1.f / 24.f) - m * m;
        smu[t] = m; srs[t] = rsqrtf(var + 1e-5f);
    }
    __syncthreads();
    size_t base = (size_t)e * 768;
    #pragma unroll
    for (int j = 0; j < 3; j++) {
        int pos = j * 256 + t;
        int g = pos / 24;
        float v = (j == 0) ? v0 : (j == 1) ? v1 : v2;
        v = fmaxf((v - smu[g]) * srs[g] * gng[pos] + gnb[pos], 0.f);
        ein[base + pos] = f2bf(v);
    }
}

// ==================================================================== CSR build, single block
__global__ __launch_bounds__(1024) void csr_kernel(
    const int* __restrict__ coli, int* __restrict__ offsets,
    int* __restrict__ elist, int N, int E)
{
    __shared__ int cnt[2048];
    __shared__ int s[1024];
    int t = threadIdx.x;
    cnt[t] = 0; cnt[1024 + t] = 0;
    __syncthreads();
    for (int e = t; e < E; e += 1024) atomicAdd(&cnt[coli[e]], 1);
    __syncthreads();
    int a = (2 * t     < N) ? cnt[2 * t]     : 0;
    int b = (2 * t + 1 < N) ? cnt[2 * t + 1] : 0;
    s[t] = a + b;
    __syncthreads();
    for (int off = 1; off < 1024; off <<= 1) {
        int v = (t >= off) ? s[t - off] : 0;
        __syncthreads();
        s[t] += v;
        __syncthreads();
    }
    int excl = (t > 0) ? s[t - 1] : 0;
    if (2 * t < N)     { offsets[2 * t]     = excl;     cnt[2 * t]     = excl; }
    if (2 * t + 1 < N) { offsets[2 * t + 1] = excl + a; cnt[2 * t + 1] = excl + a; }
    if (t == 1023) offsets[N] = s[1023];
    __syncthreads();
    for (int e = t; e < E; e += 1024) {
        int p = atomicAdd(&cnt[coli[e]], 1);
        elist[p] = e;
    }
}

// ==================================================================== attention
// block = node; wave = head (64 lanes = head dims); 1-deep K/V prefetch
__global__ __launch_bounds__(256) void attn_kernel(
    const float* __restrict__ qb, const float* __restrict__ kv,
    const int* __restrict__ offsets, const int* __restrict__ elist,
    const float* __restrict__ vbar, short* __restrict__ g_bf, int N, int E)
{
    int n = blockIdx.x;
    int c = threadIdx.x;
    float qv = qb[(size_t)n * CH + c];
    int s0 = offsets[n], s1 = offsets[n + 1];
    float out;
    if (s1 > s0) {
        float m = -INFINITY, l = 0.f, num = 0.f;
        int e = elist[s0];
        float kc = kv[(size_t)e * 512 + c];
        float vc = kv[(size_t)e * 512 + 256 + c];
        for (int idx = s0; idx < s1; idx++) {
            float kcur = kc, vcur = vc;
            if (idx + 1 < s1) {
                int e2 = elist[idx + 1];
                kc = kv[(size_t)e2 * 512 + c];
                vc = kv[(size_t)e2 * 512 + 256 + c];
            }
            float sdot = warp_sum64(qv * kcur) * 0.125f;  // 1/sqrt(64)
            float mn = fmaxf(m, sdot);
            float sc = __expf(m - mn);
            float p  = __expf(sdot - mn);
            l = l * sc + p;
            num = num * sc + p * vcur;
            m = mn;
        }
        out = num / l;
    } else {
        out = vbar[c] * (1.f / (float)E);  // 0-degree: uniform softmax over all edges
    }
    g_bf[(size_t)n * CH + c] = f2bf(out);
}

// ==================================================================== launch
extern "C" void kernel_launch(void* const* d_in, const int* in_sizes, int n_in,
                              void* d_out, int out_size, void* d_ws, size_t ws_size,
                              hipStream_t stream)
{
    const float* x       = (const float*)d_in[0];
    const int*   ei      = (const int*)d_in[1];
    const float* eattr   = (const float*)d_in[2];
    const float* gn_e1_g = (const float*)d_in[3];
    const float* gn_e1_b = (const float*)d_in[4];
    const float* We1     = (const float*)d_in[5];
    const float* be1     = (const float*)d_in[6];
    const float* gn_e2_g = (const float*)d_in[7];
    const float* gn_e2_b = (const float*)d_in[8];
    const float* We2     = (const float*)d_in[9];
    const float* be2     = (const float*)d_in[10];
    const float* gn_n_g  = (const float*)d_in[11];
    const float* gn_n_b  = (const float*)d_in[12];
    const float* Wq      = (const float*)d_in[13];
    const float* bq      = (const float*)d_in[14];
    const float* Wk      = (const float*)d_in[15];
    const float* bk      = (const float*)d_in[16];
    const float* Wv      = (const float*)d_in[17];
    const float* bv      = (const float*)d_in[18];
    const float* Wo      = (const float*)d_in[19];
    const float* bo      = (const float*)d_in[20];
    const float* Wn1     = (const float*)d_in[21];
    const float* bn1     = (const float*)d_in[22];
    const float* gn_n2_g = (const float*)d_in[23];
    const float* gn_n2_b = (const float*)d_in[24];
    const float* Wn2     = (const float*)d_in[25];
    const float* bn2     = (const float*)d_in[26];

    const int N = in_sizes[0] / CH;
    const int E = in_sizes[2] / CH;

    float* nout = (float*)d_out;                   // [N,256]
    float* eout = (float*)d_out + (size_t)N * CH;  // [E,256]

    // ---- workspace ----
    // union region: ein_bf [E,768] bf16 (dead after GEMM1)  /  kvbuf [E,512] f32
    char* base = (char*)d_ws;
    short* ein_bf = (short*)base;
    float* kvbuf  = (float*)base;
    base += (size_t)E * 512 * 4;                     // 32.77 MB (covers both)
    short* h2_bf  = (short*)base; base += (size_t)E * CH * 2;
    short* eo_bf  = (short*)base; base += (size_t)E * CH * 2;
    float* qbuf   = (float*)base; base += (size_t)N * CH * 4;
    short* g_bf   = (short*)base; base += (size_t)N * CH * 2;
    short* cat_bf = (short*)base; base += (size_t)N * 2 * CH * 2;
    short* hn_bf  = (short*)base; base += (size_t)N * CH * 2;
    short* x_bf   = (short*)base; base += (size_t)N * CH * 2;
    float* vbar   = (float*)base; base += 1024;
    float* bkv    = (float*)base; base += 2048;
    short* We1t = (short*)base; base += (size_t)768 * 256 * 2;
    short* We2t = (short*)base; base += (size_t)256 * 256 * 2;
    short* Wqt  = (short*)base; base += (size_t)256 * 256 * 2;
    short* Wkvt = (short*)base; base += (size_t)512 * 256 * 2;
    short* Wot  = (short*)base; base += (size_t)256 * 256 * 2;
    short* Wn1t = (short*)base; base += (size_t)512 * 256 * 2;
    short* Wn2t = (short*)base; base += (size_t)256 * 256 * 2;
    int* offsets = (int*)base;
    int* elist   = offsets + (N + 1) + 3;

    const int* rowi = ei;
    const int* coli = ei + E;

    dim3 blk(256);
    dim3 gE(CH / 64, E / 128);       // (4,125) edge GEMMs, 128x64 tiles
    dim3 gKV(512 / 64, E / 128);     // (8,125) fused KV
    dim3 gN(CH / 64, (N + 63) / 64); // (4,32)  node GEMMs, 64x64 tiles

    // ---- weight prep ----
    WPack wp;
    const float* wsrc[8] = {We1, We2, Wq, Wk, Wv, Wo, Wn1, Wn2};
    short* wdst[8] = {We1t, We2t, Wqt, Wkvt, Wkvt + (size_t)256 * 256, Wot, Wn1t, Wn2t};
    const int wKd[8] = {768, 256, 256, 256, 256, 256, 512, 256};
    int acc = 0;
    for (int i = 0; i < 8; i++) {
        wp.src[i] = wsrc[i]; wp.dst[i] = wdst[i]; wp.K[i] = wKd[i];
        wp.start[i] = acc; acc += wKd[i] / 16;
    }
    wconv_kernel<<<acc, blk, 0, stream>>>(wp);
    prep_kernel<<<(N + 7) / 8, blk, 0, stream>>>(x, x_bf, cat_bf, gn_n_g, gn_n_b,
                                                 vbar, bk, bv, bkv, N);
    csr_kernel<<<1, 1024, 0, stream>>>(coli, offsets, elist, N, E);

    // ---- edge model (GN+ReLU fused into GEMM1 epilogue) ----
    build_ein_kernel<<<E, blk, 0, stream>>>(x, eattr, rowi, coli, gn_e1_g, gn_e1_b, ein_bf, E);
    mfma_gemm<128, 64, 1, 0><<<gE, blk, 0, stream>>>(
        ein_bf, We1t, be1, nullptr, nullptr, h2_bf, gn_e2_g, gn_e2_b, nullptr,
        E, 3 * CH, CH, CH, 0);
    mfma_gemm<128, 64, 0, 0><<<gE, blk, 0, stream>>>(
        h2_bf, We2t, be2, eattr, eout, eo_bf, nullptr, nullptr, nullptr,
        E, CH, CH, CH, 0);

    // ---- fused KV (with vbar accumulation) + Q ----
    mfma_gemm<128, 64, 0, 1><<<gKV, blk, 0, stream>>>(
        eo_bf, Wkvt, bkv, nullptr, kvbuf, nullptr, nullptr, nullptr, vbar,
        E, CH, 512, 512, 0);
    mfma_gemm<64, 64, 0, 0><<<gN, blk, 0, stream>>>(
        x_bf, Wqt, bq, nullptr, qbuf, nullptr, nullptr, nullptr, nullptr,
        N, CH, CH, CH, 0);

    // ---- attention + Wo (writes bf16 into cat right half) ----
    attn_kernel<<<N, blk, 0, stream>>>(qbuf, kvbuf, offsets, elist, vbar, g_bf, N, E);
    mfma_gemm<64, 64, 0, 0><<<gN, blk, 0, stream>>>(
        g_bf, Wot, bo, nullptr, nullptr, cat_bf, nullptr, nullptr, nullptr,
        N, CH, CH, 2 * CH, CH);

    // ---- node MLP (GN+ReLU fused into Wn1 epilogue) ----
    mfma_gemm<64, 64, 1, 0><<<gN, blk, 0, stream>>>(
        cat_bf, Wn1t, bn1, nullptr, nullptr, hn_bf, gn_n2_g, gn_n2_b, nullptr,
        N, 2 * CH, CH, CH, 0);
    mfma_gemm<64, 64, 0, 0><<<gN, blk, 0, stream>>>(
        hn_bf, Wn2t, bn2, x, nout, nullptr, nullptr, nullptr, nullptr,
        N, CH, CH, CH, 0);
}

// Round 5
// 267.216 us; speedup vs baseline: 1.9133x; 1.0389x over previous
//
#include <hip/hip_runtime.h>
#include <hip/hip_bf16.h>
#include <stdint.h>
#include <math.h>

#define CH 256

typedef __attribute__((ext_vector_type(8)))  short short8;
typedef __attribute__((ext_vector_type(16))) short short16;
typedef __attribute__((ext_vector_type(4)))  float f32x4;

#define GL2LDS16(g, l) __builtin_amdgcn_global_load_lds(                       \
    (const __attribute__((address_space(1))) void*)(g),                        \
    (__attribute__((address_space(3))) void*)(l), 16, 0, 0)

__device__ inline short f2bf(float f) {
    __hip_bfloat16 h = __float2bfloat16(f);
    short s;
    __builtin_memcpy(&s, &h, 2);
    return s;
}

__device__ inline float warp_sum64(float v) {
    v += __shfl_xor(v, 32, 64);
    v += __shfl_xor(v, 16, 64);
    v += __shfl_xor(v, 8, 64);
    v += __shfl_xor(v, 4, 64);
    v += __shfl_xor(v, 2, 64);
    v += __shfl_xor(v, 1, 64);
    return v;
}

__device__ inline float warp_max64(float v) {
    v = fmaxf(v, __shfl_xor(v, 32, 64));
    v = fmaxf(v, __shfl_xor(v, 16, 64));
    v = fmaxf(v, __shfl_xor(v, 8, 64));
    v = fmaxf(v, __shfl_xor(v, 4, 64));
    v = fmaxf(v, __shfl_xor(v, 2, 64));
    v = fmaxf(v, __shfl_xor(v, 1, 64));
    return v;
}

// ==================================================================== MFMA GEMM
// C = A[M,K](bf16) x Bt[Nc,K](bf16) + bias, BK=64, fused epilogues.
// EPI 0: f32 out to C (opt) + res (opt) + bf16 dup to Cbf (opt)
// EPI 1: GroupNorm(groups of 8 cols)+ReLU -> bf16 to Cbf only
// VB 1:  atomically accumulate column sums of cols >=256 into vbar (KV path)
template <int BM, int BN, int EPI, int VB>
__global__ __launch_bounds__(256) void mfma_gemm(
    const short* __restrict__ A, const short* __restrict__ Bt,
    const float* __restrict__ bias, const float* __restrict__ res,
    float* __restrict__ C, short* __restrict__ Cbf,
    const float* __restrict__ gamma, const float* __restrict__ beta,
    float* __restrict__ vbar,
    int M, int K, int Nc, int ldc, int coff)
{
    constexpr int BK = 64;
    constexpr int HM = BM / 2, HN = BN / 2;   // 2x2 wave grid
    constexpr int FM = HM / 16, FN = HN / 16;
    constexpr int PA = (BM * BK) / (256 * 8); // 4KB per staging pass
    constexpr int PB = (BN * BK) / (256 * 8);
    __shared__ short As[BM * BK];
    __shared__ short Bs[BN * BK];

    const int t = threadIdx.x;
    const int wave = t >> 6, lane = t & 63;
    const int q = lane >> 4, l16 = lane & 15;
    const int row0 = blockIdx.y * BM;
    const int col0 = blockIdx.x * BN;
    const int wm = wave & 1, wn = wave >> 1;

    f32x4 acc[FM][FN];
    #pragma unroll
    for (int i = 0; i < FM; i++)
        #pragma unroll
        for (int j = 0; j < FN; j++) acc[i][j] = (f32x4){0.f, 0.f, 0.f, 0.f};

    for (int k0 = 0; k0 < K; k0 += BK) {
        #pragma unroll
        for (int p = 0; p < PA; p++) {
            int chunk = p * 256 + t;
            int r = chunk >> 3, ko = (chunk & 7) * 8;   // 8 chunks of 8 bf16 per 64-wide row
            int gr = row0 + r; if (gr >= M) gr = M - 1;
            const short* gsrc = A + (size_t)gr * K + k0 + ko;
            short* ldst = &As[(p * 256 + wave * 64) * 8];  // wave-uniform base
            GL2LDS16(gsrc, ldst);
        }
        #pragma unroll
        for (int p = 0; p < PB; p++) {
            int chunk = p * 256 + t;
            int r = chunk >> 3, ko = (chunk & 7) * 8;
            const short* gsrc = Bt + (size_t)(col0 + r) * K + k0 + ko;
            short* ldst = &Bs[(p * 256 + wave * 64) * 8];
            GL2LDS16(gsrc, ldst);
        }
        __syncthreads();
        #pragma unroll
        for (int ks = 0; ks < 2; ks++) {
            short8 af[FM], bf[FN];
            #pragma unroll
            for (int mi = 0; mi < FM; mi++)
                af[mi] = *(const short8*)&As[(wm * HM + mi * 16 + l16) * BK + ks * 32 + q * 8];
            #pragma unroll
            for (int ni = 0; ni < FN; ni++)
                bf[ni] = *(const short8*)&Bs[(wn * HN + ni * 16 + l16) * BK + ks * 32 + q * 8];
            #pragma unroll
            for (int mi = 0; mi < FM; mi++)
                #pragma unroll
                for (int ni = 0; ni < FN; ni++)
                    acc[mi][ni] = __builtin_amdgcn_mfma_f32_16x16x32_bf16(
                        af[mi], bf[ni], acc[mi][ni], 0, 0, 0);
        }
        __syncthreads();
    }

    // ---- epilogue; C/D layout: col = l16, row = q*4 + r ----
    #pragma unroll
    for (int ni = 0; ni < FN; ni++) {
        int cg = col0 + wn * HN + ni * 16 + l16;
        float bv = bias[cg];
        if constexpr (EPI == 1) {
            float ga = gamma[cg], be = beta[cg];
            #pragma unroll
            for (int mi = 0; mi < FM; mi++) {
                #pragma unroll
                for (int r = 0; r < 4; r++) {
                    float v = acc[mi][ni][r] + bv;
                    float s = v, sq = v * v;
                    s += __shfl_xor(s, 1, 64);  sq += __shfl_xor(sq, 1, 64);
                    s += __shfl_xor(s, 2, 64);  sq += __shfl_xor(sq, 2, 64);
                    s += __shfl_xor(s, 4, 64);  sq += __shfl_xor(sq, 4, 64);
                    float mean = s * 0.125f;
                    float var = sq * 0.125f - mean * mean;
                    float o = fmaxf((v - mean) * rsqrtf(var + 1e-5f) * ga + be, 0.f);
                    int rg = row0 + wm * HM + mi * 16 + q * 4 + r;
                    if (rg < M) Cbf[(size_t)rg * ldc + coff + cg] = f2bf(o);
                }
            }
        } else {
            #pragma unroll
            for (int mi = 0; mi < FM; mi++) {
                #pragma unroll
                for (int r = 0; r < 4; r++) {
                    int rg = row0 + wm * HM + mi * 16 + q * 4 + r;
                    if (rg < M) {
                        float v = acc[mi][ni][r] + bv;
                        if (res) v += res[(size_t)rg * ldc + coff + cg];
                        if (C)   C[(size_t)rg * ldc + coff + cg] = v;
                        if (Cbf) Cbf[(size_t)rg * ldc + coff + cg] = f2bf(v);
                    }
                }
            }
            if constexpr (VB) {
                if (cg >= 256) {   // V half of fused KV output
                    float part = 0.f;
                    #pragma unroll
                    for (int mi = 0; mi < FM; mi++)
                        #pragma unroll
                        for (int r = 0; r < 4; r++) {
                            int rg = row0 + wm * HM + mi * 16 + q * 4 + r;
                            if (rg < M) part += acc[mi][ni][r] + bv;
                        }
                    part += __shfl_xor(part, 16, 64);
                    part += __shfl_xor(part, 32, 64);
                    if (q == 0) atomicAdd(&vbar[cg - 256], part);
                }
            }
        }
    }
}

// ==================================================================== merged prep
// roles by blockIdx: [0,NW) weight transpose+cast; [NW,NW+NP) x prep;
// [NW+NP, NW+NP+8) zero counts. Block NW also zeroes vbar / builds bkv.
struct PrepPack {
    const float* wsrc[8];
    short* wdst[8];
    int wK[8];
    int wstart[8];      // cumulative 16-row-chunk offsets
    int NW, NP;
    const float* x;
    short* x_bf;
    short* cat_bf;
    const float* gng;
    const float* gnb;
    float* vbar;
    const float* bk;
    const float* bv;
    float* bkv;
    int* counts;
    int N;
};

__global__ __launch_bounds__(256) void prep_kernel(PrepPack p)
{
    int bid = blockIdx.x;
    int t = threadIdx.x;
    if (bid < p.NW) {
        int m = 0;
        #pragma unroll
        for (int i = 1; i < 8; i++) if (bid >= p.wstart[i]) m = i;
        int k0 = (bid - p.wstart[m]) * 16;
        const float* src = p.wsrc[m];
        short16 o;
        #pragma unroll
        for (int j = 0; j < 16; j++) o[j] = f2bf(src[(size_t)(k0 + j) * 256 + t]);
        *(short16*)(p.wdst[m] + (size_t)t * p.wK[m] + k0) = o;
        return;
    }
    if (bid >= p.NW + p.NP) {
        int i = (bid - p.NW - p.NP) * 256 + t;
        if (i < p.N) p.counts[i] = 0;
        return;
    }
    int pb = bid - p.NW;
    if (pb == 0) {
        p.vbar[t] = 0.f;
        p.bkv[t] = p.bk[t];
        p.bkv[256 + t] = p.bv[t];
    }
    int r = pb * 8 + (t >> 5);
    int g = t & 31;
    if (r >= p.N) return;
    size_t xb = (size_t)r * CH + g * 8;
    float4 a = *(const float4*)&p.x[xb];
    float4 b = *(const float4*)&p.x[xb + 4];
    short8 xr;
    xr[0] = f2bf(a.x); xr[1] = f2bf(a.y); xr[2] = f2bf(a.z); xr[3] = f2bf(a.w);
    xr[4] = f2bf(b.x); xr[5] = f2bf(b.y); xr[6] = f2bf(b.z); xr[7] = f2bf(b.w);
    *(short8*)&p.x_bf[xb] = xr;
    float s  = a.x + a.y + a.z + a.w + b.x + b.y + b.z + b.w;
    float s2 = a.x*a.x + a.y*a.y + a.z*a.z + a.w*a.w
             + b.x*b.x + b.y*b.y + b.z*b.z + b.w*b.w;
    float m = s * 0.125f;
    float var = s2 * 0.125f - m * m;
    float rsd = rsqrtf(var + 1e-5f);
    float4 g0 = *(const float4*)&p.gng[g * 8];
    float4 g1 = *(const float4*)&p.gng[g * 8 + 4];
    float4 b0 = *(const float4*)&p.gnb[g * 8];
    float4 b1 = *(const float4*)&p.gnb[g * 8 + 4];
    short8 o;
    o[0] = f2bf(fmaxf((a.x - m) * rsd * g0.x + b0.x, 0.f));
    o[1] = f2bf(fmaxf((a.y - m) * rsd * g0.y + b0.y, 0.f));
    o[2] = f2bf(fmaxf((a.z - m) * rsd * g0.z + b0.z, 0.f));
    o[3] = f2bf(fmaxf((a.w - m) * rsd * g0.w + b0.w, 0.f));
    o[4] = f2bf(fmaxf((b.x - m) * rsd * g1.x + b1.x, 0.f));
    o[5] = f2bf(fmaxf((b.y - m) * rsd * g1.y + b1.y, 0.f));
    o[6] = f2bf(fmaxf((b.z - m) * rsd * g1.z + b1.z, 0.f));
    o[7] = f2bf(fmaxf((b.w - m) * rsd * g1.w + b1.w, 0.f));
    *(short8*)&p.cat_bf[(size_t)r * (2 * CH) + g * 8] = o;
}

// ==================================================================== e_in builder (+degree count)
__global__ __launch_bounds__(256) void build_ein_kernel(
    const float* __restrict__ x, const float* __restrict__ eattr,
    const int* __restrict__ rowi, const int* __restrict__ coli,
    const float* __restrict__ gng, const float* __restrict__ gnb,
    short* __restrict__ ein, int* __restrict__ counts, int E)
{
    __shared__ float sb[768];
    __shared__ float smu[32], srs[32];
    int e = blockIdx.x, t = threadIdx.x;
    int r = rowi[e], c = coli[e];
    if (t == 0) atomicAdd(&counts[c], 1);
    float v0 = x[(size_t)r * CH + t];
    float v1 = x[(size_t)c * CH + t];
    float v2 = eattr[(size_t)e * CH + t];
    sb[t] = v0; sb[256 + t] = v1; sb[512 + t] = v2;
    __syncthreads();
    if (t < 32) {
        float s = 0.f, s2 = 0.f;
        const float* p = &sb[t * 24];
        #pragma unroll
        for (int i = 0; i < 24; i++) { float v = p[i]; s += v; s2 += v * v; }
        float m = s * (1.f / 24.f);
        float var = s2 * (1.f / 24.f) - m * m;
        smu[t] = m; srs[t] = rsqrtf(var + 1e-5f);
    }
    __syncthreads();
    size_t base = (size_t)e * 768;
    #pragma unroll
    for (int j = 0; j < 3; j++) {
        int pos = j * 256 + t;
        int g = pos / 24;
        float v = (j == 0) ? v0 : (j == 1) ? v1 : v2;
        v = fmaxf((v - smu[g]) * srs[g] * gng[pos] + gnb[pos], 0.f);
        ein[base + pos] = f2bf(v);
    }
}

// ==================================================================== scan (1 block)
__global__ __launch_bounds__(1024) void scan_kernel(
    const int* __restrict__ counts, int* __restrict__ offsets,
    int* __restrict__ cursor, int N)
{
    __shared__ int s[1024];
    int t = threadIdx.x;
    int a = (2 * t     < N) ? counts[2 * t]     : 0;
    int b = (2 * t + 1 < N) ? counts[2 * t + 1] : 0;
    s[t] = a + b;
    __syncthreads();
    for (int off = 1; off < 1024; off <<= 1) {
        int v = (t >= off) ? s[t - off] : 0;
        __syncthreads();
        s[t] += v;
        __syncthreads();
    }
    int excl = (t > 0) ? s[t - 1] : 0;
    if (2 * t < N)     { offsets[2 * t]     = excl;     cursor[2 * t]     = excl; }
    if (2 * t + 1 < N) { offsets[2 * t + 1] = excl + a; cursor[2 * t + 1] = excl + a; }
    if (t == 1023) offsets[N] = s[1023];
}

__global__ void fill_kernel(const int* __restrict__ coli, int* __restrict__ cursor,
                            int* __restrict__ elist, int E)
{
    int e = blockIdx.x * blockDim.x + threadIdx.x;
    if (e < E) {
        int p = atomicAdd(&cursor[coli[e]], 1);
        elist[p] = e;
    }
}

// ==================================================================== edge scores
// wave = edge; 4 head-dots of 64; coalesced; sc[e][h] = q[col[e]].k[e] / 8
__global__ __launch_bounds__(256) void escore_kernel(
    const float* __restrict__ qb, const float* __restrict__ kv,
    const int* __restrict__ coli, float* __restrict__ sc, int E)
{
    int e = blockIdx.x * 4 + (threadIdx.x >> 6);
    int lane = threadIdx.x & 63;
    if (e >= E) return;
    int c = coli[e];
    const float* qrow = qb + (size_t)c * CH;
    const float* krow = kv + (size_t)e * 512;
    float d0 = qrow[lane]       * krow[lane];
    float d1 = qrow[64 + lane]  * krow[64 + lane];
    float d2 = qrow[128 + lane] * krow[128 + lane];
    float d3 = qrow[192 + lane] * krow[192 + lane];
    d0 = warp_sum64(d0);
    d1 = warp_sum64(d1);
    d2 = warp_sum64(d2);
    d3 = warp_sum64(d3);
    if (lane == 0) {
        float4 o = {d0 * 0.125f, d1 * 0.125f, d2 * 0.125f, d3 * 0.125f};
        *(float4*)&sc[(size_t)e * 4] = o;
    }
}

// ==================================================================== segment softmax + PV
// block = node; wave = head; lanes = edge slots (chunked 64) then dims
__global__ __launch_bounds__(256) void attn_kernel(
    const float* __restrict__ sc, const float* __restrict__ kv,
    const int* __restrict__ offsets, const int* __restrict__ elist,
    const float* __restrict__ vbar, short* __restrict__ g_bf, int N, int E)
{
    int n = blockIdx.x;
    int h = threadIdx.x >> 6;
    int lane = threadIdx.x & 63;
    int s0 = offsets[n], s1 = offsets[n + 1];
    float out = 0.f;
    if (s1 > s0) {
        float m = -INFINITY, l = 0.f;
        for (int base = s0; base < s1; base += 64) {
            int cn = s1 - base; if (cn > 64) cn = 64;
            int e = (lane < cn) ? elist[base + lane] : 0;
            float s = (lane < cn) ? sc[(size_t)e * 4 + h] : -INFINITY;
            float mc = warp_max64(s);
            float nm = fmaxf(m, mc);
            float scale = __expf(m - nm);
            float pp = (lane < cn) ? __expf(s - nm) : 0.f;
            float ps = warp_sum64(pp);
            l = l * scale + ps;
            out *= scale;
            m = nm;
            for (int i = 0; i < cn; i++) {
                float pi = __shfl(pp, i, 64);
                int   ei = __shfl(e, i, 64);
                out += pi * kv[(size_t)ei * 512 + 256 + h * 64 + lane];
            }
        }
        out /= l;
    } else {
        out = vbar[h * 64 + lane] * (1.f / (float)E);  // 0-degree: uniform over all edges
    }
    g_bf[(size_t)n * CH + h * 64 + lane] = f2bf(out);
}

// ==================================================================== launch
extern "C" void kernel_launch(void* const* d_in, const int* in_sizes, int n_in,
                              void* d_out, int out_size, void* d_ws, size_t ws_size,
                              hipStream_t stream)
{
    const float* x       = (const float*)d_in[0];
    const int*   ei      = (const int*)d_in[1];
    const float* eattr   = (const float*)d_in[2];
    const float* gn_e1_g = (const float*)d_in[3];
    const float* gn_e1_b = (const float*)d_in[4];
    const float* We1     = (const float*)d_in[5];
    const float* be1     = (const float*)d_in[6];
    const float* gn_e2_g = (const float*)d_in[7];
    const float* gn_e2_b = (const float*)d_in[8];
    const float* We2     = (const float*)d_in[9];
    const float* be2     = (const float*)d_in[10];
    const float* gn_n_g  = (const float*)d_in[11];
    const float* gn_n_b  = (const float*)d_in[12];
    const float* Wq      = (const float*)d_in[13];
    const float* bq      = (const float*)d_in[14];
    const float* Wk      = (const float*)d_in[15];
    const float* bk      = (const float*)d_in[16];
    const float* Wv      = (const float*)d_in[17];
    const float* bv      = (const float*)d_in[18];
    const float* Wo      = (const float*)d_in[19];
    const float* bo      = (const float*)d_in[20];
    const float* Wn1     = (const float*)d_in[21];
    const float* bn1     = (const float*)d_in[22];
    const float* gn_n2_g = (const float*)d_in[23];
    const float* gn_n2_b = (const float*)d_in[24];
    const float* Wn2     = (const float*)d_in[25];
    const float* bn2     = (const float*)d_in[26];

    const int N = in_sizes[0] / CH;
    const int E = in_sizes[2] / CH;

    float* nout = (float*)d_out;                   // [N,256]
    float* eout = (float*)d_out + (size_t)N * CH;  // [E,256]

    // ---- workspace ----
    char* base = (char*)d_ws;
    short* ein_bf = (short*)base;                  // [E,768] bf16, dead after GEMM1
    float* kvbuf  = (float*)base;                  // alias: [E,512] f32
    base += (size_t)E * 512 * 4;
    short* h2_bf  = (short*)base; base += (size_t)E * CH * 2;
    short* eo_bf  = (short*)base; base += (size_t)E * CH * 2;
    float* qbuf   = (float*)base; base += (size_t)N * CH * 4;
    short* g_bf   = (short*)base; base += (size_t)N * CH * 2;
    short* cat_bf = (short*)base; base += (size_t)N * 2 * CH * 2;
    short* hn_bf  = (short*)base; base += (size_t)N * CH * 2;
    short* x_bf   = (short*)base; base += (size_t)N * CH * 2;
    float* sc     = (float*)base; base += (size_t)E * 4 * 4;
    float* vbar   = (float*)base; base += 1024;
    float* bkv    = (float*)base; base += 2048;
    short* We1t = (short*)base; base += (size_t)768 * 256 * 2;
    short* We2t = (short*)base; base += (size_t)256 * 256 * 2;
    short* Wqt  = (short*)base; base += (size_t)256 * 256 * 2;
    short* Wkvt = (short*)base; base += (size_t)512 * 256 * 2;
    short* Wot  = (short*)base; base += (size_t)256 * 256 * 2;
    short* Wn1t = (short*)base; base += (size_t)512 * 256 * 2;
    short* Wn2t = (short*)base; base += (size_t)256 * 256 * 2;
    int* counts  = (int*)base;
    int* offsets = counts + N;
    int* cursor  = offsets + (N + 1) + 3;
    int* elist   = cursor + N;

    const int* rowi = ei;
    const int* coli = ei + E;

    dim3 blk(256);
    dim3 gE(CH / 64, E / 128);       // (4,125) edge GEMMs, 128x64
    dim3 gKV(512 / 128, E / 128);    // (4,125) fused KV, 128x128
    dim3 gN(CH / 64, (N + 63) / 64); // (4,32)  node GEMMs, 64x64

    // ---- merged prep ----
    PrepPack pp;
    const float* wsrc[8] = {We1, We2, Wq, Wk, Wv, Wo, Wn1, Wn2};
    short* wdst[8] = {We1t, We2t, Wqt, Wkvt, Wkvt + (size_t)256 * 256, Wot, Wn1t, Wn2t};
    const int wKd[8] = {768, 256, 256, 256, 256, 256, 512, 256};
    int acc = 0;
    for (int i = 0; i < 8; i++) {
        pp.wsrc[i] = wsrc[i]; pp.wdst[i] = wdst[i]; pp.wK[i] = wKd[i];
        pp.wstart[i] = acc; acc += wKd[i] / 16;
    }
    pp.NW = acc;                       // 176
    pp.NP = (N + 7) / 8;               // 250
    pp.x = x; pp.x_bf = x_bf; pp.cat_bf = cat_bf;
    pp.gng = gn_n_g; pp.gnb = gn_n_b;
    pp.vbar = vbar; pp.bk = bk; pp.bv = bv; pp.bkv = bkv;
    pp.counts = counts; pp.N = N;
    int nzero = (N + 255) / 256;
    prep_kernel<<<pp.NW + pp.NP + nzero, blk, 0, stream>>>(pp);

    // ---- edge model (count fused into ein build; GN+ReLU fused into GEMM1) ----
    build_ein_kernel<<<E, blk, 0, stream>>>(x, eattr, rowi, coli, gn_e1_g, gn_e1_b,
                                            ein_bf, counts, E);
    scan_kernel<<<1, 1024, 0, stream>>>(counts, offsets, cursor, N);
    fill_kernel<<<(E + 255) / 256, blk, 0, stream>>>(coli, cursor, elist, E);

    mfma_gemm<128, 64, 1, 0><<<gE, blk, 0, stream>>>(
        ein_bf, We1t, be1, nullptr, nullptr, h2_bf, gn_e2_g, gn_e2_b, nullptr,
        E, 3 * CH, CH, CH, 0);
    mfma_gemm<128, 64, 0, 0><<<gE, blk, 0, stream>>>(
        h2_bf, We2t, be2, eattr, eout, eo_bf, nullptr, nullptr, nullptr,
        E, CH, CH, CH, 0);

    // ---- fused KV (with vbar accumulation) + Q ----
    mfma_gemm<128, 128, 0, 1><<<gKV, blk, 0, stream>>>(
        eo_bf, Wkvt, bkv, nullptr, kvbuf, nullptr, nullptr, nullptr, vbar,
        E, CH, 512, 512, 0);
    mfma_gemm<64, 64, 0, 0><<<gN, blk, 0, stream>>>(
        x_bf, Wqt, bq, nullptr, qbuf, nullptr, nullptr, nullptr, nullptr,
        N, CH, CH, CH, 0);

    // ---- attention (parallel scores, then segment softmax) ----
    escore_kernel<<<(E + 3) / 4, blk, 0, stream>>>(qbuf, kvbuf, coli, sc, E);
    attn_kernel<<<N, blk, 0, stream>>>(sc, kvbuf, offsets, elist, vbar, g_bf, N, E);
    mfma_gemm<64, 64, 0, 0><<<gN, blk, 0, stream>>>(
        g_bf, Wot, bo, nullptr, nullptr, cat_bf, nullptr, nullptr, nullptr,
        N, CH, CH, 2 * CH, CH);

    // ---- node MLP ----
    mfma_gemm<64, 64, 1, 0><<<gN, blk, 0, stream>>>(
        cat_bf, Wn1t, bn1, nullptr, nullptr, hn_bf, gn_n2_g, gn_n2_b, nullptr,
        N, 2 * CH, CH, CH, 0);
    mfma_gemm<64, 64, 0, 0><<<gN, blk, 0, stream>>>(
        hn_bf, Wn2t, bn2, x, nout, nullptr, nullptr, nullptr, nullptr,
        N, CH, CH, CH, 0);
}